// Round 1
// baseline (8538.428 us; speedup 1.0000x reference)
//
#include <hip/hip_runtime.h>
#include <math.h>

// Geometry (fixed by the reference)
#define BB   2
#define CC   64
#define HH   192
#define WW   192
#define HW   (HH*WW)          // 36864
#define HALO 3
#define HP   (HH + 2*HALO)    // 198
#define WP   (WW + 2*HALO)    // 198
#define PLANE (HP*WP)         // 39204

// ---------------------------------------------------------------------------
// 1x1 conv (64->64) with fused epilogues.
// MODE 0: out = relu(W @ X)              -> writes PADDED h layout
// MODE 1: out = relu(W @ (X * tanh(M)))  -> flat layout
// MODE 2: out = relu(W @ (X * tanh(M))) + Y0+Y1+Y2 -> flat layout
// One thread per pixel, 64 accumulators; W transposed into LDS.
// ---------------------------------------------------------------------------
template<int MODE>
__global__ __launch_bounds__(256) void conv1x1_k(
    const float* __restrict__ X, const float* __restrict__ M2,
    const float* __restrict__ W,
    const float* __restrict__ Y0, const float* __restrict__ Y1,
    const float* __restrict__ Y2,
    float* __restrict__ out)
{
    __shared__ float wl[4096];   // [c][o]
    int tid = threadIdx.x;
    #pragma unroll
    for (int n = 0; n < 16; n++) {
        int idx = tid + n*256;
        wl[(idx & 63)*64 + (idx >> 6)] = W[idx];
    }
    __syncthreads();

    int p  = blockIdx.x*256 + tid;   // [0, BB*HW)
    int b  = p / HW;
    int pp = p - b*HW;

    const float* xb = X + (size_t)b*CC*HW + pp;
    const float* mb = (MODE >= 1) ? (M2 + (size_t)b*CC*HW + pp) : nullptr;

    float acc[64];
    #pragma unroll
    for (int o = 0; o < 64; o++) acc[o] = 0.f;

    for (int c = 0; c < 64; c++) {
        float xv = xb[(size_t)c*HW];
        if (MODE >= 1) xv *= tanhf(mb[(size_t)c*HW]);
        const float4* w4 = (const float4*)(wl + c*64);
        #pragma unroll
        for (int q = 0; q < 16; q++) {
            float4 w = w4[q];
            acc[4*q+0] = fmaf(w.x, xv, acc[4*q+0]);
            acc[4*q+1] = fmaf(w.y, xv, acc[4*q+1]);
            acc[4*q+2] = fmaf(w.z, xv, acc[4*q+2]);
            acc[4*q+3] = fmaf(w.w, xv, acc[4*q+3]);
        }
    }

    if (MODE == 0) {
        int y = pp / WW, x = pp - y*WW;
        float* op = out + (size_t)b*CC*PLANE + (size_t)(y + HALO)*WP + (x + HALO);
        #pragma unroll
        for (int o = 0; o < 64; o++) op[(size_t)o*PLANE] = fmaxf(acc[o], 0.f);
    } else if (MODE == 1) {
        float* op = out + (size_t)b*CC*HW + pp;
        #pragma unroll
        for (int o = 0; o < 64; o++) op[(size_t)o*HW] = fmaxf(acc[o], 0.f);
    } else {
        float* op = out + (size_t)b*CC*HW + pp;
        int gi = b*CC*HW + pp;
        #pragma unroll
        for (int o = 0; o < 64; o++) {
            float yv = Y0[gi + o*HW] + Y1[gi + o*HW] + Y2[gi + o*HW];
            op[(size_t)o*HW] = fmaxf(acc[o], 0.f) + yv;
        }
    }
}

// ---------------------------------------------------------------------------
// Offset + mask KxK conv. Block = 64 threads (one wave), one tap-triple
// (off_y, off_x, mask) per blockIdx.y, so each input load feeds 3 FMAs and
// all weight reads are wave-uniform (scalar loads). Input is padded h.
// om layout: [B][3*K*K][HW]; channels [0,2K²) offsets, [2K²,3K²) = 2*sigmoid.
// ---------------------------------------------------------------------------
template<int K>
__global__ __launch_bounds__(64) void offmod_k(
    const float* __restrict__ hp,
    const float* __restrict__ Woff, const float* __restrict__ Boff,
    const float* __restrict__ Wmod, const float* __restrict__ Bmod,
    float* __restrict__ om)
{
    constexpr int PAD = K/2;
    constexpr int KK  = K*K;
    int t = blockIdx.y, b = blockIdx.z;
    int p = blockIdx.x*64 + threadIdx.x;
    int y = p / WW, x = p - y*WW;

    const float* wy = Woff + (size_t)(2*t  )*CC*KK;
    const float* wx = Woff + (size_t)(2*t+1)*CC*KK;
    const float* wm = Wmod + (size_t)t*CC*KK;
    float ay = Boff[2*t], ax = Boff[2*t+1], am = Bmod[t];

    const float* base = hp + (size_t)b*CC*PLANE
                          + (size_t)(y + HALO - PAD)*WP + (x + HALO - PAD);

    #pragma unroll 2
    for (int c = 0; c < 64; c++) {
        const float* bc  = base + (size_t)c*PLANE;
        const float* wyc = wy + c*KK;
        const float* wxc = wx + c*KK;
        const float* wmc = wm + c*KK;
        #pragma unroll
        for (int i = 0; i < K; i++) {
            #pragma unroll
            for (int j = 0; j < K; j++) {
                float v = bc[i*WP + j];
                int wi = i*K + j;
                ay = fmaf(wyc[wi], v, ay);
                ax = fmaf(wxc[wi], v, ax);
                am = fmaf(wmc[wi], v, am);
            }
        }
    }

    float* ob = om + (size_t)b*3*KK*HW + p;
    ob[(size_t)(2*t  )*HW] = ay;
    ob[(size_t)(2*t+1)*HW] = ax;
    ob[(size_t)(2*KK+t)*HW] = 2.f / (1.f + expf(-am));
}

// ---------------------------------------------------------------------------
// Pre-transpose w_reg [o][c][K][K] -> wt [t][c][o] so the deform kernel's
// LDS staging is coalesced and conflict-free.
// ---------------------------------------------------------------------------
template<int K>
__global__ void transpose_wreg(const float* __restrict__ Wreg,
                               float* __restrict__ wt)
{
    constexpr int KK = K*K;
    int t = blockIdx.x;
    for (int idx = threadIdx.x; idx < 4096; idx += blockDim.x) {
        int o = idx >> 6, c = idx & 63;
        wt[(size_t)t*4096 + c*64 + o] = Wreg[(size_t)(o*64 + c)*KK + t];
    }
}

// ---------------------------------------------------------------------------
// Deformable sampling + per-tap 64x64 channel matmul.
// One wave per 64-pixel tile; loops taps; per tap stages wt[t] (16 KB) into
// LDS; validity + mask folded into the 4 bilinear corner weights.
// ---------------------------------------------------------------------------
template<int K>
__global__ __launch_bounds__(64) void deform_k(
    const float* __restrict__ hp,
    const float* __restrict__ om,
    const float* __restrict__ wt,
    float* __restrict__ out)
{
    __shared__ float wl[4096];   // [c][o]
    constexpr int PAD = K/2;
    constexpr int KK  = K*K;
    int b = blockIdx.y;
    int p = blockIdx.x*64 + threadIdx.x;
    int y = p / WW, x = p - y*WW;

    float acc[64];
    #pragma unroll
    for (int o = 0; o < 64; o++) acc[o] = 0.f;

    const float* omb = om + (size_t)b*3*KK*HW + p;
    const float* hb  = hp + (size_t)b*CC*PLANE;

    for (int t = 0; t < KK; t++) {
        __syncthreads();
        #pragma unroll
        for (int n = 0; n < 64; n++)
            wl[threadIdx.x + n*64] = wt[(size_t)t*4096 + threadIdx.x + n*64];
        __syncthreads();

        int i = t / K, j = t - i*K;
        float offy = omb[(size_t)(2*t  )*HW];
        float offx = omb[(size_t)(2*t+1)*HW];
        float mk   = omb[(size_t)(2*KK+t)*HW];

        float py = (float)(y - PAD + i) + offy;
        float px = (float)(x - PAD + j) + offx;
        float fy = floorf(py), fx = floorf(px);
        float wy1 = py - fy, wx1 = px - fx;
        float wy0 = 1.f - wy1, wx0 = 1.f - wx1;
        int iy0 = (int)fy, ix0 = (int)fx;
        int iy1 = iy0 + 1, ix1 = ix0 + 1;

        float vy0 = (iy0 >= 0 && iy0 < HH) ? 1.f : 0.f;
        float vy1 = (iy1 >= 0 && iy1 < HH) ? 1.f : 0.f;
        float vx0 = (ix0 >= 0 && ix0 < WW) ? 1.f : 0.f;
        float vx1 = (ix1 >= 0 && ix1 < WW) ? 1.f : 0.f;

        int cy0 = min(max(iy0, 0), HH-1) + HALO;
        int cy1 = min(max(iy1, 0), HH-1) + HALO;
        int cx0 = min(max(ix0, 0), WW-1) + HALO;
        int cx1 = min(max(ix1, 0), WW-1) + HALO;

        float w00 = wy0*wx0*vy0*vx0*mk;
        float w01 = wy0*wx1*vy0*vx1*mk;
        float w10 = wy1*wx0*vy1*vx0*mk;
        float w11 = wy1*wx1*vy1*vx1*mk;

        int i00 = cy0*WP + cx0, i01 = cy0*WP + cx1;
        int i10 = cy1*WP + cx0, i11 = cy1*WP + cx1;

        #pragma unroll 2
        for (int c = 0; c < 64; c++) {
            const float* hc = hb + (size_t)c*PLANE;
            float s = hc[i00]*w00;
            s = fmaf(hc[i01], w01, s);
            s = fmaf(hc[i10], w10, s);
            s = fmaf(hc[i11], w11, s);
            const float4* w4 = (const float4*)(wl + c*64);
            #pragma unroll
            for (int q = 0; q < 16; q++) {
                float4 w = w4[q];
                acc[4*q+0] = fmaf(w.x, s, acc[4*q+0]);
                acc[4*q+1] = fmaf(w.y, s, acc[4*q+1]);
                acc[4*q+2] = fmaf(w.z, s, acc[4*q+2]);
                acc[4*q+3] = fmaf(w.w, s, acc[4*q+3]);
            }
        }
    }

    float* ob = out + (size_t)b*CC*HW + p;
    #pragma unroll
    for (int o = 0; o < 64; o++) ob[(size_t)o*HW] = acc[o];
}

// ---------------------------------------------------------------------------
// Launch. Workspace (floats):
//   hp : 2*64*PLANE              = 5,018,112
//   om : 2*3*49*HW               = 10,838,016   (also reused as u)
//   mm : 2*64*HW                 = 4,718,592
//   sm : 2*64*HW                 = 4,718,592
//   wt : 49*4096                 =   200,704
// total ~97.3 MiB. 'a' lives in d_out until the final two convs.
// ---------------------------------------------------------------------------
extern "C" void kernel_launch(void* const* d_in, const int* in_sizes, int n_in,
                              void* d_out, int out_size, void* d_ws, size_t ws_size,
                              hipStream_t stream)
{
    const float* x_max      = (const float*)d_in[0];
    const float* x_mid      = (const float*)d_in[1];
    const float* x_small    = (const float*)d_in[2];
    const float* w_pre_max  = (const float*)d_in[3];
    const float* w_off_max  = (const float*)d_in[4];
    const float* b_off_max  = (const float*)d_in[5];
    const float* w_mod_max  = (const float*)d_in[6];
    const float* b_mod_max  = (const float*)d_in[7];
    const float* w_reg_max  = (const float*)d_in[8];
    const float* w_pre_mid  = (const float*)d_in[9];
    const float* w_off_mid  = (const float*)d_in[10];
    const float* b_off_mid  = (const float*)d_in[11];
    const float* w_mod_mid  = (const float*)d_in[12];
    const float* b_mod_mid  = (const float*)d_in[13];
    const float* w_reg_mid  = (const float*)d_in[14];
    const float* w_pre_small= (const float*)d_in[15];
    const float* w_off_small= (const float*)d_in[16];
    const float* b_off_small= (const float*)d_in[17];
    const float* w_mod_small= (const float*)d_in[18];
    const float* b_mod_small= (const float*)d_in[19];
    const float* w_reg_small= (const float*)d_in[20];
    const float* w1         = (const float*)d_in[21];
    const float* w2         = (const float*)d_in[22];

    float* out = (float*)d_out;
    float* ws  = (float*)d_ws;
    float* hp  = ws;
    float* om  = hp + (size_t)BB*CC*PLANE;
    float* mm  = om + (size_t)BB*3*49*HW;
    float* sm  = mm + (size_t)BB*CC*HW;
    float* wt  = sm + (size_t)BB*CC*HW;
    float* u   = om;   // om dead after last deform

    hipMemsetAsync(hp, 0, (size_t)BB*CC*PLANE*sizeof(float), stream);

    const int npix_blocks = (BB*HW)/256;   // 288
    const int tile_blocks = HW/64;         // 576

    // ---- max branch (K=7) -> a in d_out
    conv1x1_k<0><<<npix_blocks, 256, 0, stream>>>(x_max, nullptr, w_pre_max,
                                                  nullptr, nullptr, nullptr, hp);
    offmod_k<7><<<dim3(tile_blocks, 49, BB), 64, 0, stream>>>(
        hp, w_off_max, b_off_max, w_mod_max, b_mod_max, om);
    transpose_wreg<7><<<49, 256, 0, stream>>>(w_reg_max, wt);
    deform_k<7><<<dim3(tile_blocks, BB), 64, 0, stream>>>(hp, om, wt, out);

    // ---- mid branch (K=5) -> mm
    conv1x1_k<0><<<npix_blocks, 256, 0, stream>>>(x_mid, nullptr, w_pre_mid,
                                                  nullptr, nullptr, nullptr, hp);
    offmod_k<5><<<dim3(tile_blocks, 25, BB), 64, 0, stream>>>(
        hp, w_off_mid, b_off_mid, w_mod_mid, b_mod_mid, om);
    transpose_wreg<5><<<25, 256, 0, stream>>>(w_reg_mid, wt);
    deform_k<5><<<dim3(tile_blocks, BB), 64, 0, stream>>>(hp, om, wt, mm);

    // ---- small branch (K=3) -> sm
    conv1x1_k<0><<<npix_blocks, 256, 0, stream>>>(x_small, nullptr, w_pre_small,
                                                  nullptr, nullptr, nullptr, hp);
    offmod_k<3><<<dim3(tile_blocks, 9, BB), 64, 0, stream>>>(
        hp, w_off_small, b_off_small, w_mod_small, b_mod_small, om);
    transpose_wreg<3><<<9, 256, 0, stream>>>(w_reg_small, wt);
    deform_k<3><<<dim3(tile_blocks, BB), 64, 0, stream>>>(hp, om, wt, sm);

    // ---- combine
    // u = relu(W1 @ (tanh(mm) * a))
    conv1x1_k<1><<<npix_blocks, 256, 0, stream>>>(out, mm, w1,
                                                  nullptr, nullptr, nullptr, u);
    // out = relu(W2 @ (tanh(sm) * u)) + (x_max + x_mid + x_small)
    conv1x1_k<2><<<npix_blocks, 256, 0, stream>>>(u, sm, w2,
                                                  x_max, x_mid, x_small, out);
}

// Round 2
// 5762.061 us; speedup vs baseline: 1.4818x; 1.4818x over previous
//
#include <hip/hip_runtime.h>
#include <math.h>

// Geometry (fixed by the reference)
#define BB   2
#define CC   64
#define HH   192
#define WW   192
#define HW   (HH*WW)          // 36864
#define HALO 3
#define HP   (HH + 2*HALO)    // 198
#define WP   (WW + 2*HALO)    // 198
#define PLANE (HP*WP)         // 39204

// ---------------------------------------------------------------------------
// 1x1 conv (64->64) with fused epilogues.
// MODE 0: out = relu(W @ X)              -> writes PADDED h layout
// MODE 1: out = relu(W @ (X * tanh(M)))  -> flat layout
// MODE 2: out = relu(W @ (X * tanh(M))) + Y0+Y1+Y2 -> flat layout
// ---------------------------------------------------------------------------
template<int MODE>
__global__ __launch_bounds__(256) void conv1x1_k(
    const float* __restrict__ X, const float* __restrict__ M2,
    const float* __restrict__ W,
    const float* __restrict__ Y0, const float* __restrict__ Y1,
    const float* __restrict__ Y2,
    float* __restrict__ out)
{
    __shared__ float wl[4096];   // [c][o]
    int tid = threadIdx.x;
    #pragma unroll
    for (int n = 0; n < 16; n++) {
        int idx = tid + n*256;
        wl[(idx & 63)*64 + (idx >> 6)] = W[idx];
    }
    __syncthreads();

    int p  = blockIdx.x*256 + tid;   // [0, BB*HW)
    int b  = p / HW;
    int pp = p - b*HW;

    const float* xb = X + (size_t)b*CC*HW + pp;
    const float* mb = (MODE >= 1) ? (M2 + (size_t)b*CC*HW + pp) : nullptr;

    float acc[64];
    #pragma unroll
    for (int o = 0; o < 64; o++) acc[o] = 0.f;

    for (int c = 0; c < 64; c++) {
        float xv = xb[(size_t)c*HW];
        if (MODE >= 1) xv *= tanhf(mb[(size_t)c*HW]);
        const float4* w4 = (const float4*)(wl + c*64);
        #pragma unroll
        for (int q = 0; q < 16; q++) {
            float4 w = w4[q];
            acc[4*q+0] = fmaf(w.x, xv, acc[4*q+0]);
            acc[4*q+1] = fmaf(w.y, xv, acc[4*q+1]);
            acc[4*q+2] = fmaf(w.z, xv, acc[4*q+2]);
            acc[4*q+3] = fmaf(w.w, xv, acc[4*q+3]);
        }
    }

    if (MODE == 0) {
        int y = pp / WW, x = pp - y*WW;
        float* op = out + (size_t)b*CC*PLANE + (size_t)(y + HALO)*WP + (x + HALO);
        #pragma unroll
        for (int o = 0; o < 64; o++) op[(size_t)o*PLANE] = fmaxf(acc[o], 0.f);
    } else if (MODE == 1) {
        float* op = out + (size_t)b*CC*HW + pp;
        #pragma unroll
        for (int o = 0; o < 64; o++) op[(size_t)o*HW] = fmaxf(acc[o], 0.f);
    } else {
        float* op = out + (size_t)b*CC*HW + pp;
        int gi = b*CC*HW + pp;
        #pragma unroll
        for (int o = 0; o < 64; o++) {
            float yv = Y0[gi + o*HW] + Y1[gi + o*HW] + Y2[gi + o*HW];
            op[(size_t)o*HW] = fmaxf(acc[o], 0.f) + yv;
        }
    }
}

// ---------------------------------------------------------------------------
// Offset + mask KxK conv. Block = 64 threads (one wave), one tap-triple
// (off_y, off_x, mask) per blockIdx.y. Input is padded h.
// ---------------------------------------------------------------------------
template<int K>
__global__ __launch_bounds__(64) void offmod_k(
    const float* __restrict__ hp,
    const float* __restrict__ Woff, const float* __restrict__ Boff,
    const float* __restrict__ Wmod, const float* __restrict__ Bmod,
    float* __restrict__ om)
{
    constexpr int PAD = K/2;
    constexpr int KK  = K*K;
    int t = blockIdx.y, b = blockIdx.z;
    int p = blockIdx.x*64 + threadIdx.x;
    int y = p / WW, x = p - y*WW;

    const float* wy = Woff + (size_t)(2*t  )*CC*KK;
    const float* wx = Woff + (size_t)(2*t+1)*CC*KK;
    const float* wm = Wmod + (size_t)t*CC*KK;
    float ay = Boff[2*t], ax = Boff[2*t+1], am = Bmod[t];

    const float* base = hp + (size_t)b*CC*PLANE
                          + (size_t)(y + HALO - PAD)*WP + (x + HALO - PAD);

    #pragma unroll 2
    for (int c = 0; c < 64; c++) {
        const float* bc  = base + (size_t)c*PLANE;
        const float* wyc = wy + c*KK;
        const float* wxc = wx + c*KK;
        const float* wmc = wm + c*KK;
        #pragma unroll
        for (int i = 0; i < K; i++) {
            #pragma unroll
            for (int j = 0; j < K; j++) {
                float v = bc[i*WP + j];
                int wi = i*K + j;
                ay = fmaf(wyc[wi], v, ay);
                ax = fmaf(wxc[wi], v, ax);
                am = fmaf(wmc[wi], v, am);
            }
        }
    }

    float* ob = om + (size_t)b*3*KK*HW + p;
    ob[(size_t)(2*t  )*HW] = ay;
    ob[(size_t)(2*t+1)*HW] = ax;
    ob[(size_t)(2*KK+t)*HW] = 2.f / (1.f + expf(-am));
}

// ---------------------------------------------------------------------------
// Pre-transpose w_reg [o][c][K][K] -> wt [t][c][o].
// ---------------------------------------------------------------------------
template<int K>
__global__ void transpose_wreg(const float* __restrict__ Wreg,
                               float* __restrict__ wt)
{
    constexpr int KK = K*K;
    int t = blockIdx.x;
    for (int idx = threadIdx.x; idx < 4096; idx += blockDim.x) {
        int o = idx >> 6, c = idx & 63;
        wt[(size_t)t*4096 + c*64 + o] = Wreg[(size_t)(o*64 + c)*KK + t];
    }
}

// ---------------------------------------------------------------------------
// Deformable sampling + per-tap 64x64 channel matmul.
// 512 threads = 8 waves = 4 px-groups (64 px) x 2 channel-halves.
// Taps staged into LDS in PAIRS (one hp gather pass feeds 2 taps).
// fp32 partial sums reduced across channel-halves via LDS (16-out chunks).
// ---------------------------------------------------------------------------
template<int K>
__global__ __launch_bounds__(512) void deform_k(
    const float* __restrict__ hp,
    const float* __restrict__ om,
    const float* __restrict__ wt,
    float* __restrict__ out)
{
    __shared__ float wl[2][4096];      // two taps: [c][o]
    __shared__ float red[4][16][64];   // [pxgroup][o_chunk][px]
    constexpr int PAD = K/2;
    constexpr int KK  = K*K;
    int b    = blockIdx.y;
    int tid  = threadIdx.x;
    int wave = tid >> 6;      // 0..7
    int lane = tid & 63;
    int pxg  = wave >> 1;     // 0..3
    int chalf= wave & 1;      // 0..1
    int p    = blockIdx.x*256 + pxg*64 + lane;
    int y    = p / WW, x = p - y*WW;

    float acc[64];
    #pragma unroll
    for (int o = 0; o < 64; o++) acc[o] = 0.f;

    const float* omb = om + (size_t)b*3*KK*HW + p;
    const float* hb  = hp + (size_t)b*CC*PLANE + (size_t)(chalf*32)*PLANE;

    auto compute_tap = [&](int t, const float* wlt) {
        int i = t / K, j = t - i*K;
        float offy = omb[(size_t)(2*t  )*HW];
        float offx = omb[(size_t)(2*t+1)*HW];
        float mk   = omb[(size_t)(2*KK+t)*HW];

        float py = (float)(y - PAD + i) + offy;
        float px = (float)(x - PAD + j) + offx;
        float fy = floorf(py), fx = floorf(px);
        float wy1 = py - fy, wx1 = px - fx;
        float wy0 = 1.f - wy1, wx0 = 1.f - wx1;
        int iy0 = (int)fy, ix0 = (int)fx;
        int iy1 = iy0 + 1, ix1 = ix0 + 1;

        float vy0 = (iy0 >= 0 && iy0 < HH) ? 1.f : 0.f;
        float vy1 = (iy1 >= 0 && iy1 < HH) ? 1.f : 0.f;
        float vx0 = (ix0 >= 0 && ix0 < WW) ? 1.f : 0.f;
        float vx1 = (ix1 >= 0 && ix1 < WW) ? 1.f : 0.f;

        int cy0 = min(max(iy0, 0), HH-1) + HALO;
        int cy1 = min(max(iy1, 0), HH-1) + HALO;
        int cx0 = min(max(ix0, 0), WW-1) + HALO;
        int cx1 = min(max(ix1, 0), WW-1) + HALO;

        float w00 = wy0*wx0*vy0*vx0*mk;
        float w01 = wy0*wx1*vy0*vx1*mk;
        float w10 = wy1*wx0*vy1*vx0*mk;
        float w11 = wy1*wx1*vy1*vx1*mk;

        int i00 = cy0*WP + cx0, i01 = cy0*WP + cx1;
        int i10 = cy1*WP + cx0, i11 = cy1*WP + cx1;

        const float* wbase = wlt + (size_t)(chalf*32)*64;
        #pragma unroll 2
        for (int c = 0; c < 32; c++) {
            const float* hc = hb + (size_t)c*PLANE;
            float s = hc[i00]*w00;
            s = fmaf(hc[i01], w01, s);
            s = fmaf(hc[i10], w10, s);
            s = fmaf(hc[i11], w11, s);
            const float4* w4 = (const float4*)(wbase + c*64);
            #pragma unroll
            for (int q = 0; q < 16; q++) {
                float4 w = w4[q];
                acc[4*q+0] = fmaf(w.x, s, acc[4*q+0]);
                acc[4*q+1] = fmaf(w.y, s, acc[4*q+1]);
                acc[4*q+2] = fmaf(w.z, s, acc[4*q+2]);
                acc[4*q+3] = fmaf(w.w, s, acc[4*q+3]);
            }
        }
    };

    // tap pairs
    for (int tt = 0; tt + 1 < KK; tt += 2) {
        __syncthreads();
        const float* src = wt + (size_t)tt*4096;
        #pragma unroll
        for (int n = 0; n < 16; n++)
            wl[0][tid + n*512] = src[tid + n*512];
        __syncthreads();
        compute_tap(tt,   wl[0]);
        compute_tap(tt+1, wl[1]);
    }
    // tail tap (KK is odd)
    {
        __syncthreads();
        const float* src = wt + (size_t)(KK-1)*4096;
        #pragma unroll
        for (int n = 0; n < 8; n++)
            wl[0][tid + n*512] = src[tid + n*512];
        __syncthreads();
        compute_tap(KK-1, wl[0]);
    }

    // cross-half reduction + store, 16 outputs at a time
    float* ob = out + (size_t)b*CC*HW + p;
    for (int oc = 0; oc < 64; oc += 16) {
        __syncthreads();
        if (chalf == 1) {
            #pragma unroll
            for (int o = 0; o < 16; o++) red[pxg][o][lane] = acc[oc+o];
        }
        __syncthreads();
        if (chalf == 0) {
            #pragma unroll
            for (int o = 0; o < 16; o++)
                ob[(size_t)(oc+o)*HW] = acc[oc+o] + red[pxg][o][lane];
        }
    }
}

// ---------------------------------------------------------------------------
// Launch. Workspace (floats):
//   hp : 2*64*PLANE = 5,018,112
//   om : 2*3*49*HW  = 10,838,016   (reused as u after last deform)
//   mm : 2*64*HW    = 4,718,592
//   sm : 2*64*HW    = 4,718,592
//   wt : 49*4096    =   200,704
// ---------------------------------------------------------------------------
extern "C" void kernel_launch(void* const* d_in, const int* in_sizes, int n_in,
                              void* d_out, int out_size, void* d_ws, size_t ws_size,
                              hipStream_t stream)
{
    const float* x_max      = (const float*)d_in[0];
    const float* x_mid      = (const float*)d_in[1];
    const float* x_small    = (const float*)d_in[2];
    const float* w_pre_max  = (const float*)d_in[3];
    const float* w_off_max  = (const float*)d_in[4];
    const float* b_off_max  = (const float*)d_in[5];
    const float* w_mod_max  = (const float*)d_in[6];
    const float* b_mod_max  = (const float*)d_in[7];
    const float* w_reg_max  = (const float*)d_in[8];
    const float* w_pre_mid  = (const float*)d_in[9];
    const float* w_off_mid  = (const float*)d_in[10];
    const float* b_off_mid  = (const float*)d_in[11];
    const float* w_mod_mid  = (const float*)d_in[12];
    const float* b_mod_mid  = (const float*)d_in[13];
    const float* w_reg_mid  = (const float*)d_in[14];
    const float* w_pre_small= (const float*)d_in[15];
    const float* w_off_small= (const float*)d_in[16];
    const float* b_off_small= (const float*)d_in[17];
    const float* w_mod_small= (const float*)d_in[18];
    const float* b_mod_small= (const float*)d_in[19];
    const float* w_reg_small= (const float*)d_in[20];
    const float* w1         = (const float*)d_in[21];
    const float* w2         = (const float*)d_in[22];

    float* out = (float*)d_out;
    float* ws  = (float*)d_ws;
    float* hp  = ws;
    float* om  = hp + (size_t)BB*CC*PLANE;
    float* mm  = om + (size_t)BB*3*49*HW;
    float* sm  = mm + (size_t)BB*CC*HW;
    float* wt  = sm + (size_t)BB*CC*HW;
    float* u   = om;   // om dead after last deform

    hipMemsetAsync(hp, 0, (size_t)BB*CC*PLANE*sizeof(float), stream);

    const int npix_blocks = (BB*HW)/256;   // 288
    const int tile_blocks = HW/64;         // 576
    const int dfm_blocks  = HW/256;        // 144

    // ---- max branch (K=7) -> a in d_out
    conv1x1_k<0><<<npix_blocks, 256, 0, stream>>>(x_max, nullptr, w_pre_max,
                                                  nullptr, nullptr, nullptr, hp);
    offmod_k<7><<<dim3(tile_blocks, 49, BB), 64, 0, stream>>>(
        hp, w_off_max, b_off_max, w_mod_max, b_mod_max, om);
    transpose_wreg<7><<<49, 256, 0, stream>>>(w_reg_max, wt);
    deform_k<7><<<dim3(dfm_blocks, BB), 512, 0, stream>>>(hp, om, wt, out);

    // ---- mid branch (K=5) -> mm
    conv1x1_k<0><<<npix_blocks, 256, 0, stream>>>(x_mid, nullptr, w_pre_mid,
                                                  nullptr, nullptr, nullptr, hp);
    offmod_k<5><<<dim3(tile_blocks, 25, BB), 64, 0, stream>>>(
        hp, w_off_mid, b_off_mid, w_mod_mid, b_mod_mid, om);
    transpose_wreg<5><<<25, 256, 0, stream>>>(w_reg_mid, wt);
    deform_k<5><<<dim3(dfm_blocks, BB), 512, 0, stream>>>(hp, om, wt, mm);

    // ---- small branch (K=3) -> sm
    conv1x1_k<0><<<npix_blocks, 256, 0, stream>>>(x_small, nullptr, w_pre_small,
                                                  nullptr, nullptr, nullptr, hp);
    offmod_k<3><<<dim3(tile_blocks, 9, BB), 64, 0, stream>>>(
        hp, w_off_small, b_off_small, w_mod_small, b_mod_small, om);
    transpose_wreg<3><<<9, 256, 0, stream>>>(w_reg_small, wt);
    deform_k<3><<<dim3(dfm_blocks, BB), 512, 0, stream>>>(hp, om, wt, sm);

    // ---- combine
    conv1x1_k<1><<<npix_blocks, 256, 0, stream>>>(out, mm, w1,
                                                  nullptr, nullptr, nullptr, u);
    conv1x1_k<2><<<npix_blocks, 256, 0, stream>>>(u, sm, w2,
                                                  x_max, x_mid, x_small, out);
}

// Round 3
// 1984.608 us; speedup vs baseline: 4.3023x; 2.9034x over previous
//
#include <hip/hip_runtime.h>
#include <math.h>

// Geometry (fixed by the reference)
#define BB   2
#define CC   64
#define HH   192
#define WW   192
#define HW   (HH*WW)          // 36864
#define HALO 3
#define HP   (HH + 2*HALO)    // 198
#define WP   (WW + 2*HALO)    // 198
#define PLANE (HP*WP)         // 39204

// ---------------------------------------------------------------------------
// 1x1 conv (64->64) with fused epilogues.
// MODE 0: out = relu(W @ X)              -> writes PADDED h layout
// MODE 1: out = relu(W @ (X * tanh(M)))  -> flat layout
// MODE 2: out = relu(W @ (X * tanh(M))) + Y0+Y1+Y2 -> flat layout
// ---------------------------------------------------------------------------
template<int MODE>
__global__ __launch_bounds__(256) void conv1x1_k(
    const float* __restrict__ X, const float* __restrict__ M2,
    const float* __restrict__ W,
    const float* __restrict__ Y0, const float* __restrict__ Y1,
    const float* __restrict__ Y2,
    float* __restrict__ out)
{
    __shared__ float wl[4096];   // [c][o]
    int tid = threadIdx.x;
    #pragma unroll
    for (int n = 0; n < 16; n++) {
        int idx = tid + n*256;
        wl[(idx & 63)*64 + (idx >> 6)] = W[idx];
    }
    __syncthreads();

    int p  = blockIdx.x*256 + tid;   // [0, BB*HW)
    int b  = p / HW;
    int pp = p - b*HW;

    const float* xb = X + (size_t)b*CC*HW + pp;
    const float* mb = (MODE >= 1) ? (M2 + (size_t)b*CC*HW + pp) : nullptr;

    float acc[64];
    #pragma unroll
    for (int o = 0; o < 64; o++) acc[o] = 0.f;

    for (int c = 0; c < 64; c++) {
        float xv = xb[(size_t)c*HW];
        if (MODE >= 1) xv *= tanhf(mb[(size_t)c*HW]);
        const float4* w4 = (const float4*)(wl + c*64);
        #pragma unroll
        for (int q = 0; q < 16; q++) {
            float4 w = w4[q];
            acc[4*q+0] = fmaf(w.x, xv, acc[4*q+0]);
            acc[4*q+1] = fmaf(w.y, xv, acc[4*q+1]);
            acc[4*q+2] = fmaf(w.z, xv, acc[4*q+2]);
            acc[4*q+3] = fmaf(w.w, xv, acc[4*q+3]);
        }
    }

    if (MODE == 0) {
        int y = pp / WW, x = pp - y*WW;
        float* op = out + (size_t)b*CC*PLANE + (size_t)(y + HALO)*WP + (x + HALO);
        #pragma unroll
        for (int o = 0; o < 64; o++) op[(size_t)o*PLANE] = fmaxf(acc[o], 0.f);
    } else if (MODE == 1) {
        float* op = out + (size_t)b*CC*HW + pp;
        #pragma unroll
        for (int o = 0; o < 64; o++) op[(size_t)o*HW] = fmaxf(acc[o], 0.f);
    } else {
        float* op = out + (size_t)b*CC*HW + pp;
        int gi = b*CC*HW + pp;
        #pragma unroll
        for (int o = 0; o < 64; o++) {
            float yv = Y0[gi + o*HW] + Y1[gi + o*HW] + Y2[gi + o*HW];
            op[(size_t)o*HW] = fmaxf(acc[o], 0.f) + yv;
        }
    }
}

// ---------------------------------------------------------------------------
// Offset + mask KxK conv, LDS-tiled.
// Block = 256 threads = one 16x16 pixel tile. Loops channels in chunks of 8,
// staging the (16+2*PAD)^2 input window per channel chunk into LDS.
// Weights packed [tap][c][{wy,wx,wm,0}] in LDS (uniform b128 broadcast reads).
// Tap-batches across blockIdx.y keep accumulator arrays compile-time sized.
// ---------------------------------------------------------------------------
template<int K, int TB>
__global__ __launch_bounds__(256) void offmod_tile_k(
    const float* __restrict__ hp,
    const float* __restrict__ Woff, const float* __restrict__ Boff,
    const float* __restrict__ Wmod, const float* __restrict__ Bmod,
    float* __restrict__ om)
{
    constexpr int PAD   = K/2;
    constexpr int KK    = K*K;
    constexpr int TD    = 16 + 2*PAD;
    constexpr int CCH   = 8;
    constexpr int NTAPS = (KK + TB - 1)/TB;

    __shared__ float tile[CCH][TD][TD];
    __shared__ float wb[NTAPS][CC][4];

    int bx = blockIdx.x;           // 0..(HW/256-1)
    int g  = blockIdx.y;           // tap batch
    int b  = blockIdx.z;
    int tx = bx % (WW/16), ty = bx / (WW/16);
    int x0 = tx*16, y0 = ty*16;
    int tid = threadIdx.x;
    int lx = tid & 15, ly = tid >> 4;
    int t0 = g*NTAPS;

    // stage packed weights for this tap batch (all 64 channels)
    for (int idx = tid; idx < NTAPS*CC; idx += 256) {
        int t = idx / CC, c = idx - (idx/CC)*CC;
        int tap = min(t0 + t, KK-1);
        wb[t][c][0] = Woff[(size_t)(2*tap  )*CC*KK + c*KK + tap];
        wb[t][c][1] = Woff[(size_t)(2*tap+1)*CC*KK + c*KK + tap];
        wb[t][c][2] = Wmod[(size_t)tap*CC*KK + c*KK + tap];
        wb[t][c][3] = 0.f;
    }

    float accy[NTAPS], accx[NTAPS], accm[NTAPS];
    #pragma unroll
    for (int t = 0; t < NTAPS; t++) {
        int tap = min(t0 + t, KK-1);
        accy[t] = Boff[2*tap];
        accx[t] = Boff[2*tap+1];
        accm[t] = Bmod[tap];
    }

    for (int cc = 0; cc < CC; cc += CCH) {
        __syncthreads();   // protect tile overwrite (and wb on first iter)
        constexpr int TSZ = CCH*TD*TD;
        for (int idx = tid; idx < TSZ; idx += 256) {
            int c   = idx / (TD*TD);
            int rem = idx - c*(TD*TD);
            int r   = rem / TD;
            int col = rem - r*TD;
            tile[c][r][col] = hp[(size_t)(b*CC + cc + c)*PLANE
                                 + (size_t)(y0 + HALO - PAD + r)*WP
                                 + (x0 + HALO - PAD + col)];
        }
        __syncthreads();

        #pragma unroll
        for (int c = 0; c < CCH; c++) {
            #pragma unroll
            for (int t = 0; t < NTAPS; t++) {
                int tap = min(t0 + t, KK-1);
                int i = tap / K, j = tap - (tap/K)*K;
                float v = tile[c][ly + i][lx + j];
                float4 w = *(const float4*)&wb[t][cc + c][0];
                accy[t] = fmaf(w.x, v, accy[t]);
                accx[t] = fmaf(w.y, v, accx[t]);
                accm[t] = fmaf(w.z, v, accm[t]);
            }
        }
    }

    int px = (y0 + ly)*WW + x0 + lx;
    float* ob = om + (size_t)b*3*KK*HW + px;
    #pragma unroll
    for (int t = 0; t < NTAPS; t++) {
        int tap = t0 + t;
        if (tap < KK) {
            ob[(size_t)(2*tap  )*HW] = accy[t];
            ob[(size_t)(2*tap+1)*HW] = accx[t];
            ob[(size_t)(2*KK+tap)*HW] = 2.f / (1.f + expf(-accm[t]));
        }
    }
}

// ---------------------------------------------------------------------------
// Pre-transpose w_reg [o][c][K][K] -> wt [t][c][o].
// ---------------------------------------------------------------------------
template<int K>
__global__ void transpose_wreg(const float* __restrict__ Wreg,
                               float* __restrict__ wt)
{
    constexpr int KK = K*K;
    int t = blockIdx.x;
    for (int idx = threadIdx.x; idx < 4096; idx += blockDim.x) {
        int o = idx >> 6, c = idx & 63;
        wt[(size_t)t*4096 + c*64 + o] = Wreg[(size_t)(o*64 + c)*KK + t];
    }
}

// ---------------------------------------------------------------------------
// Deformable sampling + per-tap 64x64 channel matmul.
// 512 threads = 8 waves = 4 px-groups (64 px) x 2 channel-halves.
// Tap-GROUPS across blockIdx.y (G groups) for occupancy; partial results
// combined via fp32 atomicAdd into zeroed output.
// Taps staged into LDS in PAIRS; gathers batched 4 channels at a time.
// ---------------------------------------------------------------------------
template<int K, int G>
__global__ __launch_bounds__(512) void deform_k(
    const float* __restrict__ hp,
    const float* __restrict__ om,
    const float* __restrict__ wt,
    float* __restrict__ out)
{
    __shared__ float wl[2][4096];      // two taps: [c][o]
    __shared__ float red[4][16][64];   // [pxgroup][o_chunk][px]
    constexpr int PAD = K/2;
    constexpr int KK  = K*K;
    int b    = blockIdx.z;
    int g    = blockIdx.y;
    int tid  = threadIdx.x;
    int wave = tid >> 6;
    int lane = tid & 63;
    int pxg  = wave >> 1;
    int chalf= wave & 1;
    int p    = blockIdx.x*256 + pxg*64 + lane;
    int y    = p / WW, x = p - y*WW;

    int t0 = (KK*g)/G, t1 = (KK*(g+1))/G;

    float acc[64];
    #pragma unroll
    for (int o = 0; o < 64; o++) acc[o] = 0.f;

    const float* omb = om + (size_t)b*3*KK*HW + p;
    const float* hb  = hp + (size_t)b*CC*PLANE + (size_t)(chalf*32)*PLANE;

    auto compute_tap = [&](int t, const float* wlt) {
        int i = t / K, j = t - (t/K)*K;
        float offy = omb[(size_t)(2*t  )*HW];
        float offx = omb[(size_t)(2*t+1)*HW];
        float mk   = omb[(size_t)(2*KK+t)*HW];

        float py = (float)(y - PAD + i) + offy;
        float px = (float)(x - PAD + j) + offx;
        float fy = floorf(py), fx = floorf(px);
        float wy1 = py - fy, wx1 = px - fx;
        float wy0 = 1.f - wy1, wx0 = 1.f - wx1;
        int iy0 = (int)fy, ix0 = (int)fx;
        int iy1 = iy0 + 1, ix1 = ix0 + 1;

        float vy0 = (iy0 >= 0 && iy0 < HH) ? 1.f : 0.f;
        float vy1 = (iy1 >= 0 && iy1 < HH) ? 1.f : 0.f;
        float vx0 = (ix0 >= 0 && ix0 < WW) ? 1.f : 0.f;
        float vx1 = (ix1 >= 0 && ix1 < WW) ? 1.f : 0.f;

        int cy0 = min(max(iy0, 0), HH-1) + HALO;
        int cy1 = min(max(iy1, 0), HH-1) + HALO;
        int cx0 = min(max(ix0, 0), WW-1) + HALO;
        int cx1 = min(max(ix1, 0), WW-1) + HALO;

        float w00 = wy0*wx0*vy0*vx0*mk;
        float w01 = wy0*wx1*vy0*vx1*mk;
        float w10 = wy1*wx0*vy1*vx0*mk;
        float w11 = wy1*wx1*vy1*vx1*mk;

        int i00 = cy0*WP + cx0, i01 = cy0*WP + cx1;
        int i10 = cy1*WP + cx0, i11 = cy1*WP + cx1;

        const float* wbase = wlt + (size_t)(chalf*32)*64;
        #pragma unroll 1
        for (int c4 = 0; c4 < 32; c4 += 4) {
            float v[4][4];
            #pragma unroll
            for (int u = 0; u < 4; u++) {
                const float* hc = hb + (size_t)(c4+u)*PLANE;
                v[u][0] = hc[i00]; v[u][1] = hc[i01];
                v[u][2] = hc[i10]; v[u][3] = hc[i11];
            }
            #pragma unroll
            for (int u = 0; u < 4; u++) {
                float s = v[u][0]*w00;
                s = fmaf(v[u][1], w01, s);
                s = fmaf(v[u][2], w10, s);
                s = fmaf(v[u][3], w11, s);
                const float4* w4 = (const float4*)(wbase + (c4+u)*64);
                #pragma unroll
                for (int q = 0; q < 16; q++) {
                    float4 w = w4[q];
                    acc[4*q+0] = fmaf(w.x, s, acc[4*q+0]);
                    acc[4*q+1] = fmaf(w.y, s, acc[4*q+1]);
                    acc[4*q+2] = fmaf(w.z, s, acc[4*q+2]);
                    acc[4*q+3] = fmaf(w.w, s, acc[4*q+3]);
                }
            }
        }
    };

    int t = t0;
    for (; t + 1 < t1; t += 2) {
        __syncthreads();
        const float* src = wt + (size_t)t*4096;
        #pragma unroll
        for (int n = 0; n < 16; n++)
            wl[0][tid + n*512] = src[tid + n*512];
        __syncthreads();
        compute_tap(t,   wl[0]);
        compute_tap(t+1, wl[1]);
    }
    if (t < t1) {
        __syncthreads();
        const float* src = wt + (size_t)t*4096;
        #pragma unroll
        for (int n = 0; n < 8; n++)
            wl[0][tid + n*512] = src[tid + n*512];
        __syncthreads();
        compute_tap(t, wl[0]);
    }

    // cross-half reduction, then one atomicAdd per output element
    float* ob = out + (size_t)b*CC*HW + p;
    for (int oc = 0; oc < 64; oc += 16) {
        __syncthreads();
        if (chalf == 1) {
            #pragma unroll
            for (int o = 0; o < 16; o++) red[pxg][o][lane] = acc[oc+o];
        }
        __syncthreads();
        if (chalf == 0) {
            #pragma unroll
            for (int o = 0; o < 16; o++)
                atomicAdd(&ob[(size_t)(oc+o)*HW], acc[oc+o] + red[pxg][o][lane]);
        }
    }
}

// ---------------------------------------------------------------------------
// Launch. Workspace (floats):
//   hp : 2*64*PLANE = 5,018,112
//   om : 2*3*49*HW  = 10,838,016   (reused as u after last deform)
//   mm : 2*64*HW    = 4,718,592
//   sm : 2*64*HW    = 4,718,592
//   wt : 49*4096    =   200,704
// ---------------------------------------------------------------------------
extern "C" void kernel_launch(void* const* d_in, const int* in_sizes, int n_in,
                              void* d_out, int out_size, void* d_ws, size_t ws_size,
                              hipStream_t stream)
{
    const float* x_max      = (const float*)d_in[0];
    const float* x_mid      = (const float*)d_in[1];
    const float* x_small    = (const float*)d_in[2];
    const float* w_pre_max  = (const float*)d_in[3];
    const float* w_off_max  = (const float*)d_in[4];
    const float* b_off_max  = (const float*)d_in[5];
    const float* w_mod_max  = (const float*)d_in[6];
    const float* b_mod_max  = (const float*)d_in[7];
    const float* w_reg_max  = (const float*)d_in[8];
    const float* w_pre_mid  = (const float*)d_in[9];
    const float* w_off_mid  = (const float*)d_in[10];
    const float* b_off_mid  = (const float*)d_in[11];
    const float* w_mod_mid  = (const float*)d_in[12];
    const float* b_mod_mid  = (const float*)d_in[13];
    const float* w_reg_mid  = (const float*)d_in[14];
    const float* w_pre_small= (const float*)d_in[15];
    const float* w_off_small= (const float*)d_in[16];
    const float* b_off_small= (const float*)d_in[17];
    const float* w_mod_small= (const float*)d_in[18];
    const float* b_mod_small= (const float*)d_in[19];
    const float* w_reg_small= (const float*)d_in[20];
    const float* w1         = (const float*)d_in[21];
    const float* w2         = (const float*)d_in[22];

    float* out = (float*)d_out;
    float* ws  = (float*)d_ws;
    float* hp  = ws;
    float* om  = hp + (size_t)BB*CC*PLANE;
    float* mm  = om + (size_t)BB*3*49*HW;
    float* sm  = mm + (size_t)BB*CC*HW;
    float* wt  = sm + (size_t)BB*CC*HW;
    float* u   = om;   // om dead after last deform

    hipMemsetAsync(hp, 0, (size_t)BB*CC*PLANE*sizeof(float), stream);
    hipMemsetAsync(out, 0, (size_t)BB*CC*HW*sizeof(float), stream);
    hipMemsetAsync(mm, 0, (size_t)BB*CC*HW*sizeof(float), stream);
    hipMemsetAsync(sm, 0, (size_t)BB*CC*HW*sizeof(float), stream);

    const int npix_blocks = (BB*HW)/256;   // 288
    const int tile_blocks = HW/256;        // 144 (16x16 px tiles)
    const int dfm_blocks  = HW/256;        // 144

    // ---- max branch (K=7) -> a accumulated in d_out
    conv1x1_k<0><<<npix_blocks, 256, 0, stream>>>(x_max, nullptr, w_pre_max,
                                                  nullptr, nullptr, nullptr, hp);
    offmod_tile_k<7,4><<<dim3(tile_blocks, 4, BB), 256, 0, stream>>>(
        hp, w_off_max, b_off_max, w_mod_max, b_mod_max, om);
    transpose_wreg<7><<<49, 256, 0, stream>>>(w_reg_max, wt);
    deform_k<7,4><<<dim3(dfm_blocks, 4, BB), 512, 0, stream>>>(hp, om, wt, out);

    // ---- mid branch (K=5) -> mm
    conv1x1_k<0><<<npix_blocks, 256, 0, stream>>>(x_mid, nullptr, w_pre_mid,
                                                  nullptr, nullptr, nullptr, hp);
    offmod_tile_k<5,2><<<dim3(tile_blocks, 2, BB), 256, 0, stream>>>(
        hp, w_off_mid, b_off_mid, w_mod_mid, b_mod_mid, om);
    transpose_wreg<5><<<25, 256, 0, stream>>>(w_reg_mid, wt);
    deform_k<5,4><<<dim3(dfm_blocks, 4, BB), 512, 0, stream>>>(hp, om, wt, mm);

    // ---- small branch (K=3) -> sm
    conv1x1_k<0><<<npix_blocks, 256, 0, stream>>>(x_small, nullptr, w_pre_small,
                                                  nullptr, nullptr, nullptr, hp);
    offmod_tile_k<3,1><<<dim3(tile_blocks, 1, BB), 256, 0, stream>>>(
        hp, w_off_small, b_off_small, w_mod_small, b_mod_small, om);
    transpose_wreg<3><<<9, 256, 0, stream>>>(w_reg_small, wt);
    deform_k<3,2><<<dim3(dfm_blocks, 2, BB), 512, 0, stream>>>(hp, om, wt, sm);

    // ---- combine
    conv1x1_k<1><<<npix_blocks, 256, 0, stream>>>(out, mm, w1,
                                                  nullptr, nullptr, nullptr, u);
    conv1x1_k<2><<<npix_blocks, 256, 0, stream>>>(u, sm, w2,
                                                  x_max, x_mid, x_small, out);
}

// Round 4
// 1525.680 us; speedup vs baseline: 5.5965x; 1.3008x over previous
//
#include <hip/hip_runtime.h>
#include <math.h>

// Geometry (fixed by the reference)
#define BB   2
#define CC   64
#define HH   192
#define WW   192
#define HW   (HH*WW)          // 36864
#define HALO 3
#define HP   (HH + 2*HALO)    // 198
#define WP   (WW + 2*HALO)    // 198
#define PLANE (HP*WP)         // 39204

typedef __attribute__((ext_vector_type(8))) short bf16x8;
typedef __attribute__((ext_vector_type(4))) float f32x4;

__device__ __forceinline__ unsigned short f2bf(float f) {
    union { float f; unsigned u; } x; x.f = f;
    unsigned r = (x.u + 0x7fffu + ((x.u >> 16) & 1u)) >> 16;   // RNE
    return (unsigned short)r;
}

__device__ __forceinline__ float fast_tanh(float x) {
    // tanh(x) = 1 - 2/(e^{2x}+1)
    float e = __expf(2.f * x);
    return 1.f - 2.f * __builtin_amdgcn_rcpf(e + 1.f);
}

// ---------------------------------------------------------------------------
// 1x1 conv (64->64) with fused epilogues, split 2-way over outputs.
// MODE 0: out = relu(W @ X)              -> writes PADDED h layout
// MODE 1: out = relu(W @ (X * tanh(M)))  -> flat layout
// MODE 2: out = relu(W @ (X * tanh(M))) + Y0+Y1+Y2 -> flat layout
// ---------------------------------------------------------------------------
template<int MODE>
__global__ __launch_bounds__(256) void conv1x1_k(
    const float* __restrict__ X, const float* __restrict__ M2,
    const float* __restrict__ W,
    const float* __restrict__ Y0, const float* __restrict__ Y1,
    const float* __restrict__ Y2,
    float* __restrict__ out)
{
    __shared__ float wl[64*32];   // [c][o_half]
    int tid = threadIdx.x;
    int oh  = blockIdx.y;         // output half
    #pragma unroll
    for (int n = 0; n < 8; n++) {
        int idx = tid + n*256;            // [0,2048)
        int op  = idx >> 6, c = idx & 63;
        wl[c*32 + op] = W[(size_t)(oh*32 + op)*64 + c];
    }
    __syncthreads();

    int p  = blockIdx.x*256 + tid;   // [0, BB*HW)
    int b  = p / HW;
    int pp = p - b*HW;

    const float* xb = X + (size_t)b*CC*HW + pp;
    const float* mb = (MODE >= 1) ? (M2 + (size_t)b*CC*HW + pp) : nullptr;

    float acc[32];
    #pragma unroll
    for (int o = 0; o < 32; o++) acc[o] = 0.f;

    for (int c = 0; c < 64; c++) {
        float xv = xb[(size_t)c*HW];
        if (MODE >= 1) xv *= fast_tanh(mb[(size_t)c*HW]);
        const float4* w4 = (const float4*)(wl + c*32);
        #pragma unroll
        for (int q = 0; q < 8; q++) {
            float4 w = w4[q];
            acc[4*q+0] = fmaf(w.x, xv, acc[4*q+0]);
            acc[4*q+1] = fmaf(w.y, xv, acc[4*q+1]);
            acc[4*q+2] = fmaf(w.z, xv, acc[4*q+2]);
            acc[4*q+3] = fmaf(w.w, xv, acc[4*q+3]);
        }
    }

    if (MODE == 0) {
        int y = pp / WW, x = pp - y*WW;
        float* op = out + (size_t)b*CC*PLANE + (size_t)(oh*32)*PLANE
                        + (size_t)(y + HALO)*WP + (x + HALO);
        #pragma unroll
        for (int o = 0; o < 32; o++) op[(size_t)o*PLANE] = fmaxf(acc[o], 0.f);
    } else if (MODE == 1) {
        float* op = out + (size_t)b*CC*HW + (size_t)(oh*32)*HW + pp;
        #pragma unroll
        for (int o = 0; o < 32; o++) op[(size_t)o*HW] = fmaxf(acc[o], 0.f);
    } else {
        float* op = out + (size_t)b*CC*HW + (size_t)(oh*32)*HW + pp;
        size_t gi = (size_t)b*CC*HW + (size_t)(oh*32)*HW + pp;
        #pragma unroll
        for (int o = 0; o < 32; o++) {
            float yv = Y0[gi + (size_t)o*HW] + Y1[gi + (size_t)o*HW] + Y2[gi + (size_t)o*HW];
            op[(size_t)o*HW] = fmaxf(acc[o], 0.f) + yv;
        }
    }
}

// ---------------------------------------------------------------------------
// Offset + mask KxK conv, LDS-tiled. (unchanged from round 3)
// ---------------------------------------------------------------------------
template<int K, int TB>
__global__ __launch_bounds__(256) void offmod_tile_k(
    const float* __restrict__ hp,
    const float* __restrict__ Woff, const float* __restrict__ Boff,
    const float* __restrict__ Wmod, const float* __restrict__ Bmod,
    float* __restrict__ om)
{
    constexpr int PAD   = K/2;
    constexpr int KK    = K*K;
    constexpr int TD    = 16 + 2*PAD;
    constexpr int CCH   = 8;
    constexpr int NTAPS = (KK + TB - 1)/TB;

    __shared__ float tile[CCH][TD][TD];
    __shared__ float wb[NTAPS][CC][4];

    int bx = blockIdx.x;
    int g  = blockIdx.y;
    int b  = blockIdx.z;
    int tx = bx % (WW/16), ty = bx / (WW/16);
    int x0 = tx*16, y0 = ty*16;
    int tid = threadIdx.x;
    int lx = tid & 15, ly = tid >> 4;
    int t0 = g*NTAPS;

    for (int idx = tid; idx < NTAPS*CC; idx += 256) {
        int t = idx / CC, c = idx - (idx/CC)*CC;
        int tap = min(t0 + t, KK-1);
        wb[t][c][0] = Woff[(size_t)(2*tap  )*CC*KK + c*KK + tap];
        wb[t][c][1] = Woff[(size_t)(2*tap+1)*CC*KK + c*KK + tap];
        wb[t][c][2] = Wmod[(size_t)tap*CC*KK + c*KK + tap];
        wb[t][c][3] = 0.f;
    }

    float accy[NTAPS], accx[NTAPS], accm[NTAPS];
    #pragma unroll
    for (int t = 0; t < NTAPS; t++) {
        int tap = min(t0 + t, KK-1);
        accy[t] = Boff[2*tap];
        accx[t] = Boff[2*tap+1];
        accm[t] = Bmod[tap];
    }

    for (int cc = 0; cc < CC; cc += CCH) {
        __syncthreads();
        constexpr int TSZ = CCH*TD*TD;
        for (int idx = tid; idx < TSZ; idx += 256) {
            int c   = idx / (TD*TD);
            int rem = idx - c*(TD*TD);
            int r   = rem / TD;
            int col = rem - r*TD;
            tile[c][r][col] = hp[(size_t)(b*CC + cc + c)*PLANE
                                 + (size_t)(y0 + HALO - PAD + r)*WP
                                 + (x0 + HALO - PAD + col)];
        }
        __syncthreads();

        #pragma unroll
        for (int c = 0; c < CCH; c++) {
            #pragma unroll
            for (int t = 0; t < NTAPS; t++) {
                int tap = min(t0 + t, KK-1);
                int i = tap / K, j = tap - (tap/K)*K;
                float v = tile[c][ly + i][lx + j];
                float4 w = *(const float4*)&wb[t][cc + c][0];
                accy[t] = fmaf(w.x, v, accy[t]);
                accx[t] = fmaf(w.y, v, accx[t]);
                accm[t] = fmaf(w.z, v, accm[t]);
            }
        }
    }

    int px = (y0 + ly)*WW + x0 + lx;
    float* ob = om + (size_t)b*3*KK*HW + px;
    #pragma unroll
    for (int t = 0; t < NTAPS; t++) {
        int tap = t0 + t;
        if (tap < KK) {
            ob[(size_t)(2*tap  )*HW] = accy[t];
            ob[(size_t)(2*tap+1)*HW] = accx[t];
            ob[(size_t)(2*KK+tap)*HW] = 2.f * __builtin_amdgcn_rcpf(1.f + __expf(-accm[t]));
        }
    }
}

// ---------------------------------------------------------------------------
// Pre-bake w_reg [o][c][K][K] into MFMA B-fragment order, bf16:
// wtb[t][kk*4+ot][lane] = bf16x8 of B[k = kk*32+(lane>>4)*8+j][o = ot*16+(lane&15)]
// where B[c][o] = w_reg[o][c][tap t].
// ---------------------------------------------------------------------------
template<int K>
__global__ __launch_bounds__(512) void make_wtb_k(
    const float* __restrict__ Wreg, bf16x8* __restrict__ wtb)
{
    constexpr int KK = K*K;
    int t   = blockIdx.x;
    int tid = threadIdx.x;            // [0,512)
    int kk  = tid >> 8;
    int rem = tid & 255;
    int ot  = rem >> 6;
    int l   = rem & 63;
    int lr  = l & 15, lg = l >> 4;
    int o   = ot*16 + lr;
    bf16x8 v;
    #pragma unroll
    for (int j = 0; j < 8; j++) {
        int c = kk*32 + lg*8 + j;
        v[j] = (short)f2bf(Wreg[((size_t)o*CC + c)*KK + t]);
    }
    wtb[(size_t)t*8*64 + (size_t)(kk*4 + ot)*64 + l] = v;
}

// ---------------------------------------------------------------------------
// Deformable sampling + MFMA channel matmul.
// Block = 256 thr = 4 waves. Wave w handles 16 pixels (pxbase..+15) x 64 outs.
// Per tap: each lane gathers its A-fragment (px = lane&15, c = (lane>>4)*8+j,
// two K-halves) straight into registers; B-fragments read coalesced from wtb;
// 8 MFMA accumulate out[px][o] over all taps and channels. Direct stores.
// ---------------------------------------------------------------------------
template<int K>
__global__ __launch_bounds__(256) void deform_mfma_k(
    const float* __restrict__ hp,
    const float* __restrict__ om,
    const bf16x8* __restrict__ wtb,
    float* __restrict__ out)
{
    constexpr int PAD = K/2;
    constexpr int KK  = K*K;
    int b    = blockIdx.y;
    int tid  = threadIdx.x;
    int wave = tid >> 6;
    int l    = tid & 63;
    int lg   = l >> 4;        // lane group 0..3
    int lr   = l & 15;
    int pxbase = blockIdx.x*64 + wave*16;
    int px   = pxbase + lr;   // pixel this lane samples (A-row)
    int y    = px / WW, x = px - y*WW;

    f32x4 acc[4];
    #pragma unroll
    for (int ot = 0; ot < 4; ot++) acc[ot] = (f32x4)0.f;

    const float* omb = om + (size_t)b*3*KK*HW + px;
    const float* hb  = hp + (size_t)b*CC*PLANE;

    #pragma unroll 1
    for (int t = 0; t < KK; t++) {
        int i = t / K, j = t - (t/K)*K;
        float offy = omb[(size_t)(2*t  )*HW];
        float offx = omb[(size_t)(2*t+1)*HW];
        float mk   = omb[(size_t)(2*KK+t)*HW];

        float py = (float)(y - PAD + i) + offy;
        float pxf= (float)(x - PAD + j) + offx;
        float fy = floorf(py), fx = floorf(pxf);
        float wy1 = py - fy, wx1 = pxf - fx;
        float wy0 = 1.f - wy1, wx0 = 1.f - wx1;
        int iy0 = (int)fy, ix0 = (int)fx;
        int iy1 = iy0 + 1, ix1 = ix0 + 1;

        float vy0 = (iy0 >= 0 && iy0 < HH) ? 1.f : 0.f;
        float vy1 = (iy1 >= 0 && iy1 < HH) ? 1.f : 0.f;
        float vx0 = (ix0 >= 0 && ix0 < WW) ? 1.f : 0.f;
        float vx1 = (ix1 >= 0 && ix1 < WW) ? 1.f : 0.f;

        int cy0 = min(max(iy0, 0), HH-1) + HALO;
        int cy1 = min(max(iy1, 0), HH-1) + HALO;
        int cx0 = min(max(ix0, 0), WW-1) + HALO;
        int cx1 = min(max(ix1, 0), WW-1) + HALO;

        float w00 = wy0*wx0*vy0*vx0*mk;
        float w01 = wy0*wx1*vy0*vx1*mk;
        float w10 = wy1*wx0*vy1*vx1*mk;   // placeholder fixed below
        w10 = wy1*wx0*vy1*vx0*mk;
        float w11 = wy1*wx1*vy1*vx1*mk;

        int i00 = cy0*WP + cx0, i01 = cy0*WP + cx1;
        int i10 = cy1*WP + cx0, i11 = cy1*WP + cx1;

        // gather A-fragments: two K-halves of 8 channels each
        bf16x8 afrag[2];
        #pragma unroll
        for (int kk = 0; kk < 2; kk++) {
            const float* hbase = hb + (size_t)(kk*32 + lg*8)*PLANE;
            #pragma unroll
            for (int j8 = 0; j8 < 8; j8++) {
                const float* hc = hbase + (size_t)j8*PLANE;
                float s = hc[i00]*w00;
                s = fmaf(hc[i01], w01, s);
                s = fmaf(hc[i10], w10, s);
                s = fmaf(hc[i11], w11, s);
                afrag[kk][j8] = (short)f2bf(s);
            }
        }

        const bf16x8* bp = wtb + (size_t)t*8*64 + l;
        #pragma unroll
        for (int kk = 0; kk < 2; kk++) {
            #pragma unroll
            for (int ot = 0; ot < 4; ot++) {
                acc[ot] = __builtin_amdgcn_mfma_f32_16x16x32_bf16(
                    afrag[kk], bp[(size_t)(kk*4 + ot)*64], acc[ot], 0, 0, 0);
            }
        }
    }

    // C/D layout: o = ot*16 + (lane&15), px = pxbase + (lane>>4)*4 + reg
    float* ob = out + (size_t)b*CC*HW + pxbase + lg*4;
    #pragma unroll
    for (int ot = 0; ot < 4; ot++) {
        float4 v;
        v.x = acc[ot][0]; v.y = acc[ot][1]; v.z = acc[ot][2]; v.w = acc[ot][3];
        *reinterpret_cast<float4*>(ob + (size_t)(ot*16 + lr)*HW) = v;
    }
}

// ---------------------------------------------------------------------------
// Launch. Workspace (floats):
//   hp : 2*64*PLANE = 5,018,112
//   om : 2*3*49*HW  = 10,838,016   (reused as u after last deform)
//   mm : 2*64*HW    = 4,718,592
//   sm : 2*64*HW    = 4,718,592
//   wtb: 49*8*64*8 bf16 = 100,352 float-slots
// ---------------------------------------------------------------------------
extern "C" void kernel_launch(void* const* d_in, const int* in_sizes, int n_in,
                              void* d_out, int out_size, void* d_ws, size_t ws_size,
                              hipStream_t stream)
{
    const float* x_max      = (const float*)d_in[0];
    const float* x_mid      = (const float*)d_in[1];
    const float* x_small    = (const float*)d_in[2];
    const float* w_pre_max  = (const float*)d_in[3];
    const float* w_off_max  = (const float*)d_in[4];
    const float* b_off_max  = (const float*)d_in[5];
    const float* w_mod_max  = (const float*)d_in[6];
    const float* b_mod_max  = (const float*)d_in[7];
    const float* w_reg_max  = (const float*)d_in[8];
    const float* w_pre_mid  = (const float*)d_in[9];
    const float* w_off_mid  = (const float*)d_in[10];
    const float* b_off_mid  = (const float*)d_in[11];
    const float* w_mod_mid  = (const float*)d_in[12];
    const float* b_mod_mid  = (const float*)d_in[13];
    const float* w_reg_mid  = (const float*)d_in[14];
    const float* w_pre_small= (const float*)d_in[15];
    const float* w_off_small= (const float*)d_in[16];
    const float* b_off_small= (const float*)d_in[17];
    const float* w_mod_small= (const float*)d_in[18];
    const float* b_mod_small= (const float*)d_in[19];
    const float* w_reg_small= (const float*)d_in[20];
    const float* w1         = (const float*)d_in[21];
    const float* w2         = (const float*)d_in[22];

    float* out = (float*)d_out;
    float* ws  = (float*)d_ws;
    float* hp  = ws;
    float* om  = hp + (size_t)BB*CC*PLANE;
    float* mm  = om + (size_t)BB*3*49*HW;
    float* sm  = mm + (size_t)BB*CC*HW;
    bf16x8* wtb= (bf16x8*)(sm + (size_t)BB*CC*HW);
    float* u   = om;   // om dead after last deform

    hipMemsetAsync(hp, 0, (size_t)BB*CC*PLANE*sizeof(float), stream);

    const int npix_blocks = (BB*HW)/256;   // 288
    const int tile_blocks = HW/256;        // 144 (16x16 px tiles)
    const int dfm_blocks  = HW/64;         // 576 (64-px strips)

    // ---- max branch (K=7) -> a in d_out
    conv1x1_k<0><<<dim3(npix_blocks,2), 256, 0, stream>>>(x_max, nullptr, w_pre_max,
                                                  nullptr, nullptr, nullptr, hp);
    offmod_tile_k<7,4><<<dim3(tile_blocks, 4, BB), 256, 0, stream>>>(
        hp, w_off_max, b_off_max, w_mod_max, b_mod_max, om);
    make_wtb_k<7><<<49, 512, 0, stream>>>(w_reg_max, wtb);
    deform_mfma_k<7><<<dim3(dfm_blocks, BB), 256, 0, stream>>>(hp, om, wtb, out);

    // ---- mid branch (K=5) -> mm
    conv1x1_k<0><<<dim3(npix_blocks,2), 256, 0, stream>>>(x_mid, nullptr, w_pre_mid,
                                                  nullptr, nullptr, nullptr, hp);
    offmod_tile_k<5,2><<<dim3(tile_blocks, 2, BB), 256, 0, stream>>>(
        hp, w_off_mid, b_off_mid, w_mod_mid, b_mod_mid, om);
    make_wtb_k<5><<<25, 512, 0, stream>>>(w_reg_mid, wtb);
    deform_mfma_k<5><<<dim3(dfm_blocks, BB), 256, 0, stream>>>(hp, om, wtb, mm);

    // ---- small branch (K=3) -> sm
    conv1x1_k<0><<<dim3(npix_blocks,2), 256, 0, stream>>>(x_small, nullptr, w_pre_small,
                                                  nullptr, nullptr, nullptr, hp);
    offmod_tile_k<3,1><<<dim3(tile_blocks, 1, BB), 256, 0, stream>>>(
        hp, w_off_small, b_off_small, w_mod_small, b_mod_small, om);
    make_wtb_k<3><<<9, 512, 0, stream>>>(w_reg_small, wtb);
    deform_mfma_k<3><<<dim3(dfm_blocks, BB), 256, 0, stream>>>(hp, om, wtb, sm);

    // ---- combine
    conv1x1_k<1><<<dim3(npix_blocks,2), 256, 0, stream>>>(out, mm, w1,
                                                  nullptr, nullptr, nullptr, u);
    conv1x1_k<2><<<dim3(npix_blocks,2), 256, 0, stream>>>(u, sm, w2,
                                                  x_max, x_mid, x_small, out);
}

// Round 5
// 1011.002 us; speedup vs baseline: 8.4455x; 1.5091x over previous
//
#include <hip/hip_runtime.h>
#include <math.h>

// Geometry (fixed by the reference)
#define BB   2
#define CC   64
#define HH   192
#define WW   192
#define HW   (HH*WW)          // 36864
#define HALO 3
#define HP   (HH + 2*HALO)    // 198
#define WP   (WW + 2*HALO)    // 198
#define PLANE (HP*WP)         // 39204

typedef __attribute__((ext_vector_type(8))) short bf16x8;
typedef __attribute__((ext_vector_type(4))) float f32x4;

__device__ __forceinline__ unsigned short f2bf(float f) {
    union { float f; unsigned u; } x; x.f = f;
    unsigned r = (x.u + 0x7fffu + ((x.u >> 16) & 1u)) >> 16;   // RNE
    return (unsigned short)r;
}

__device__ __forceinline__ float fast_tanh(float x) {
    float e = __expf(2.f * x);
    return 1.f - 2.f * __builtin_amdgcn_rcpf(e + 1.f);
}

// ---------------------------------------------------------------------------
// 1x1 conv (64->64) with fused epilogues, split 2-way over outputs.
// MODE 0: out = relu(W @ X)              -> writes PADDED h layout
// MODE 1: out = relu(W @ (X * tanh(M)))  -> flat layout
// MODE 2: out = relu(W @ (X * tanh(M))) + Y0+Y1+Y2 -> flat layout
// ---------------------------------------------------------------------------
template<int MODE>
__global__ __launch_bounds__(256) void conv1x1_k(
    const float* __restrict__ X, const float* __restrict__ M2,
    const float* __restrict__ W,
    const float* __restrict__ Y0, const float* __restrict__ Y1,
    const float* __restrict__ Y2,
    float* __restrict__ out)
{
    __shared__ float wl[64*32];   // [c][o_half]
    int tid = threadIdx.x;
    int oh  = blockIdx.y;         // output half
    #pragma unroll
    for (int n = 0; n < 8; n++) {
        int idx = tid + n*256;            // [0,2048)
        int op  = idx >> 6, c = idx & 63;
        wl[c*32 + op] = W[(size_t)(oh*32 + op)*64 + c];
    }
    __syncthreads();

    int p  = blockIdx.x*256 + tid;   // [0, BB*HW)
    int b  = p / HW;
    int pp = p - b*HW;

    const float* xb = X + (size_t)b*CC*HW + pp;
    const float* mb = (MODE >= 1) ? (M2 + (size_t)b*CC*HW + pp) : nullptr;

    float acc[32];
    #pragma unroll
    for (int o = 0; o < 32; o++) acc[o] = 0.f;

    for (int c = 0; c < 64; c++) {
        float xv = xb[(size_t)c*HW];
        if (MODE >= 1) xv *= fast_tanh(mb[(size_t)c*HW]);
        const float4* w4 = (const float4*)(wl + c*32);
        #pragma unroll
        for (int q = 0; q < 8; q++) {
            float4 w = w4[q];
            acc[4*q+0] = fmaf(w.x, xv, acc[4*q+0]);
            acc[4*q+1] = fmaf(w.y, xv, acc[4*q+1]);
            acc[4*q+2] = fmaf(w.z, xv, acc[4*q+2]);
            acc[4*q+3] = fmaf(w.w, xv, acc[4*q+3]);
        }
    }

    if (MODE == 0) {
        int y = pp / WW, x = pp - y*WW;
        float* op = out + (size_t)b*CC*PLANE + (size_t)(oh*32)*PLANE
                        + (size_t)(y + HALO)*WP + (x + HALO);
        #pragma unroll
        for (int o = 0; o < 32; o++) op[(size_t)o*PLANE] = fmaxf(acc[o], 0.f);
    } else if (MODE == 1) {
        float* op = out + (size_t)b*CC*HW + (size_t)(oh*32)*HW + pp;
        #pragma unroll
        for (int o = 0; o < 32; o++) op[(size_t)o*HW] = fmaxf(acc[o], 0.f);
    } else {
        float* op = out + (size_t)b*CC*HW + (size_t)(oh*32)*HW + pp;
        size_t gi = (size_t)b*CC*HW + (size_t)(oh*32)*HW + pp;
        #pragma unroll
        for (int o = 0; o < 32; o++) {
            float yv = Y0[gi + (size_t)o*HW] + Y1[gi + (size_t)o*HW] + Y2[gi + (size_t)o*HW];
            op[(size_t)o*HW] = fmaxf(acc[o], 0.f) + yv;
        }
    }
}

// ---------------------------------------------------------------------------
// Offset + mask KxK conv, LDS-tiled, XCD-swizzled 1D grid.
// grid = B * 144 * G blocks; swz order: b outer, tile middle, g inner so each
// XCD chunk covers a contiguous band of tile rows (L2-resident hp slice).
// ---------------------------------------------------------------------------
template<int K, int TB>
__global__ __launch_bounds__(256) void offmod_tile_k(
    const float* __restrict__ hp,
    const float* __restrict__ Woff, const float* __restrict__ Boff,
    const float* __restrict__ Wmod, const float* __restrict__ Bmod,
    float* __restrict__ om)
{
    constexpr int PAD   = K/2;
    constexpr int KK    = K*K;
    constexpr int TD    = 16 + 2*PAD;
    constexpr int CCH   = 8;
    constexpr int NTAPS = (KK + TB - 1)/TB;
    constexpr int NT    = HW/256;   // 144 tiles

    __shared__ float tile[CCH][TD][TD];
    __shared__ float wb[NTAPS][CC][4];

    int raw = blockIdx.x;
    int N   = BB*NT*TB;
    int swz = (raw & 7)*(N >> 3) + (raw >> 3);
    int g   = swz % TB;
    int rem = swz / TB;
    int bt  = rem % NT;
    int b   = rem / NT;

    int tx = bt % (WW/16), ty = bt / (WW/16);
    int x0 = tx*16, y0 = ty*16;
    int tid = threadIdx.x;
    int lx = tid & 15, ly = tid >> 4;
    int t0 = g*NTAPS;

    for (int idx = tid; idx < NTAPS*CC; idx += 256) {
        int t = idx / CC, c = idx - (idx/CC)*CC;
        int tap = min(t0 + t, KK-1);
        wb[t][c][0] = Woff[(size_t)(2*tap  )*CC*KK + c*KK + tap];
        wb[t][c][1] = Woff[(size_t)(2*tap+1)*CC*KK + c*KK + tap];
        wb[t][c][2] = Wmod[(size_t)tap*CC*KK + c*KK + tap];
        wb[t][c][3] = 0.f;
    }

    float accy[NTAPS], accx[NTAPS], accm[NTAPS];
    #pragma unroll
    for (int t = 0; t < NTAPS; t++) {
        int tap = min(t0 + t, KK-1);
        accy[t] = Boff[2*tap];
        accx[t] = Boff[2*tap+1];
        accm[t] = Bmod[tap];
    }

    for (int cc = 0; cc < CC; cc += CCH) {
        __syncthreads();
        constexpr int TSZ = CCH*TD*TD;
        for (int idx = tid; idx < TSZ; idx += 256) {
            int c   = idx / (TD*TD);
            int rem2= idx - c*(TD*TD);
            int r   = rem2 / TD;
            int col = rem2 - r*TD;
            tile[c][r][col] = hp[(size_t)(b*CC + cc + c)*PLANE
                                 + (size_t)(y0 + HALO - PAD + r)*WP
                                 + (x0 + HALO - PAD + col)];
        }
        __syncthreads();

        #pragma unroll
        for (int c = 0; c < CCH; c++) {
            #pragma unroll
            for (int t = 0; t < NTAPS; t++) {
                int tap = min(t0 + t, KK-1);
                int i = tap / K, j = tap - (tap/K)*K;
                float v = tile[c][ly + i][lx + j];
                float4 w = *(const float4*)&wb[t][cc + c][0];
                accy[t] = fmaf(w.x, v, accy[t]);
                accx[t] = fmaf(w.y, v, accx[t]);
                accm[t] = fmaf(w.z, v, accm[t]);
            }
        }
    }

    int px = (y0 + ly)*WW + x0 + lx;
    float* ob = om + (size_t)b*3*KK*HW + px;
    #pragma unroll
    for (int t = 0; t < NTAPS; t++) {
        int tap = t0 + t;
        if (tap < KK) {
            ob[(size_t)(2*tap  )*HW] = accy[t];
            ob[(size_t)(2*tap+1)*HW] = accx[t];
            ob[(size_t)(2*KK+tap)*HW] = 2.f * __builtin_amdgcn_rcpf(1.f + __expf(-accm[t]));
        }
    }
}

// ---------------------------------------------------------------------------
// Pre-bake w_reg [o][c][K][K] into MFMA B-fragment order, bf16.
// ---------------------------------------------------------------------------
template<int K>
__global__ __launch_bounds__(512) void make_wtb_k(
    const float* __restrict__ Wreg, bf16x8* __restrict__ wtb)
{
    constexpr int KK = K*K;
    int t   = blockIdx.x;
    int tid = threadIdx.x;
    int kk  = tid >> 8;
    int rem = tid & 255;
    int ot  = rem >> 6;
    int l   = rem & 63;
    int lr  = l & 15, lg = l >> 4;
    int o   = ot*16 + lr;
    bf16x8 v;
    #pragma unroll
    for (int j = 0; j < 8; j++) {
        int c = kk*32 + lg*8 + j;
        v[j] = (short)f2bf(Wreg[((size_t)o*CC + c)*KK + t]);
    }
    wtb[(size_t)t*8*64 + (size_t)(kk*4 + ot)*64 + l] = v;
}

// ---------------------------------------------------------------------------
// Deformable sampling + MFMA channel matmul.
// 512 thr = 8 waves: pxg = wave&3 (16-px group), half = wave>>2 (tap half).
// XCD-swizzled 1D grid (each XCD: contiguous 48-row band, hp slice ~2.8MB
// L2-resident). Corner loads: one base addr per channel, offsets 0/4/792/796;
// clamp to [-1,192] provably lands in the zero halo, so no validity masks.
// Tap-half partials reduced via LDS; direct float4 stores.
// ---------------------------------------------------------------------------
template<int K>
__global__ __launch_bounds__(512) void deform_mfma_k(
    const float* __restrict__ hp,
    const float* __restrict__ om,
    const bf16x8* __restrict__ wtb,
    float* __restrict__ out)
{
    constexpr int PAD = K/2;
    constexpr int KK  = K*K;
    constexpr int NB  = HW/64;      // 576 strips per batch
    __shared__ float red[4][64][16];   // [pxg][o][px]

    int raw = blockIdx.x;            // [0, 2*NB)
    int swz = (raw & 7)*((2*NB) >> 3) + (raw >> 3);
    int b = swz / NB, strip = swz - b*NB;

    int tid  = threadIdx.x;
    int wave = tid >> 6;
    int l    = tid & 63;
    int lg   = l >> 4;
    int lr   = l & 15;
    int pxg  = wave & 3;
    int half = wave >> 2;
    int pxbase = strip*64 + pxg*16;
    int px   = pxbase + lr;
    int y    = px / WW, x = px - y*WW;

    int t0 = half ? (KK/2) : 0;
    int t1 = half ? KK : (KK/2);

    f32x4 acc[4];
    #pragma unroll
    for (int ot = 0; ot < 4; ot++) acc[ot] = (f32x4)0.f;

    const float* omb = om + (size_t)b*3*KK*HW + px;
    const float* hb  = hp + (size_t)b*CC*PLANE;

    #pragma unroll 1
    for (int t = t0; t < t1; t++) {
        int i = t / K, j = t - (t/K)*K;
        float offy = omb[(size_t)(2*t  )*HW];
        float offx = omb[(size_t)(2*t+1)*HW];
        float mk   = omb[(size_t)(2*KK+t)*HW];

        float py = (float)(y - PAD + i) + offy;
        float pxf= (float)(x - PAD + j) + offx;
        float fy = floorf(py), fx = floorf(pxf);
        float wy1 = py - fy, wx1 = pxf - fx;
        float wy0 = 1.f - wy1, wx0 = 1.f - wx1;
        int iy0 = (int)fy, ix0 = (int)fx;

        // clamp to [-1, 192]: clamped loads land in the zero halo, and for
        // coords in [-1,192] the padded plane equals the masked reference.
        int Y0 = min(max(iy0, -1), HH) + HALO;   // [2,195]
        int X0 = min(max(ix0, -1), WW) + HALO;   // [2,195]
        int r0 = Y0*WP + X0;

        float w00 = wy0*wx0*mk;
        float w01 = wy0*wx1*mk;
        float w10 = wy1*wx0*mk;
        float w11 = wy1*wx1*mk;

        bf16x8 afrag[2];
        #pragma unroll
        for (int kk = 0; kk < 2; kk++) {
            const float* hbase = hb + (size_t)(kk*32 + lg*8)*PLANE + r0;
            #pragma unroll
            for (int j8 = 0; j8 < 8; j8++) {
                const float* hc = hbase + (size_t)j8*PLANE;
                float s = hc[0]*w00;
                s = fmaf(hc[1],    w01, s);
                s = fmaf(hc[WP],   w10, s);
                s = fmaf(hc[WP+1], w11, s);
                afrag[kk][j8] = (short)f2bf(s);
            }
        }

        const bf16x8* bp = wtb + (size_t)t*8*64 + l;
        #pragma unroll
        for (int kk = 0; kk < 2; kk++) {
            #pragma unroll
            for (int ot = 0; ot < 4; ot++) {
                acc[ot] = __builtin_amdgcn_mfma_f32_16x16x32_bf16(
                    afrag[kk], bp[(size_t)(kk*4 + ot)*64], acc[ot], 0, 0, 0);
            }
        }
    }

    // reduce tap halves through LDS, then store.
    // C/D layout: o = ot*16 + lr, px = pxbase + lg*4 + reg
    if (half == 1) {
        #pragma unroll
        for (int ot = 0; ot < 4; ot++)
            *reinterpret_cast<f32x4*>(&red[pxg][ot*16 + lr][lg*4]) = acc[ot];
    }
    __syncthreads();
    if (half == 0) {
        float* ob = out + (size_t)b*CC*HW + pxbase + lg*4;
        #pragma unroll
        for (int ot = 0; ot < 4; ot++) {
            f32x4 r = *reinterpret_cast<const f32x4*>(&red[pxg][ot*16 + lr][lg*4]);
            r += acc[ot];
            float4 v;
            v.x = r[0]; v.y = r[1]; v.z = r[2]; v.w = r[3];
            *reinterpret_cast<float4*>(ob + (size_t)(ot*16 + lr)*HW) = v;
        }
    }
}

// ---------------------------------------------------------------------------
// Launch. Workspace (floats):
//   hp : 2*64*PLANE = 5,018,112
//   om : 2*3*49*HW  = 10,838,016   (reused as u after last deform)
//   mm : 2*64*HW    = 4,718,592
//   sm : 2*64*HW    = 4,718,592
//   wtb: 49*512 bf16x8 = 100,352 float-slots
// ---------------------------------------------------------------------------
extern "C" void kernel_launch(void* const* d_in, const int* in_sizes, int n_in,
                              void* d_out, int out_size, void* d_ws, size_t ws_size,
                              hipStream_t stream)
{
    const float* x_max      = (const float*)d_in[0];
    const float* x_mid      = (const float*)d_in[1];
    const float* x_small    = (const float*)d_in[2];
    const float* w_pre_max  = (const float*)d_in[3];
    const float* w_off_max  = (const float*)d_in[4];
    const float* b_off_max  = (const float*)d_in[5];
    const float* w_mod_max  = (const float*)d_in[6];
    const float* b_mod_max  = (const float*)d_in[7];
    const float* w_reg_max  = (const float*)d_in[8];
    const float* w_pre_mid  = (const float*)d_in[9];
    const float* w_off_mid  = (const float*)d_in[10];
    const float* b_off_mid  = (const float*)d_in[11];
    const float* w_mod_mid  = (const float*)d_in[12];
    const float* b_mod_mid  = (const float*)d_in[13];
    const float* w_reg_mid  = (const float*)d_in[14];
    const float* w_pre_small= (const float*)d_in[15];
    const float* w_off_small= (const float*)d_in[16];
    const float* b_off_small= (const float*)d_in[17];
    const float* w_mod_small= (const float*)d_in[18];
    const float* b_mod_small= (const float*)d_in[19];
    const float* w_reg_small= (const float*)d_in[20];
    const float* w1         = (const float*)d_in[21];
    const float* w2         = (const float*)d_in[22];

    float* out = (float*)d_out;
    float* ws  = (float*)d_ws;
    float* hp  = ws;
    float* om  = hp + (size_t)BB*CC*PLANE;
    float* mm  = om + (size_t)BB*3*49*HW;
    float* sm  = mm + (size_t)BB*CC*HW;
    bf16x8* wtb= (bf16x8*)(sm + (size_t)BB*CC*HW);
    float* u   = om;   // om dead after last deform

    hipMemsetAsync(hp, 0, (size_t)BB*CC*PLANE*sizeof(float), stream);

    const int npix_blocks = (BB*HW)/256;   // 288
    const int dfm_blocks  = BB*(HW/64);    // 1152

    // ---- max branch (K=7) -> a in d_out
    conv1x1_k<0><<<dim3(npix_blocks,2), 256, 0, stream>>>(x_max, nullptr, w_pre_max,
                                                  nullptr, nullptr, nullptr, hp);
    offmod_tile_k<7,4><<<BB*144*4, 256, 0, stream>>>(
        hp, w_off_max, b_off_max, w_mod_max, b_mod_max, om);
    make_wtb_k<7><<<49, 512, 0, stream>>>(w_reg_max, wtb);
    deform_mfma_k<7><<<dfm_blocks, 512, 0, stream>>>(hp, om, wtb, out);

    // ---- mid branch (K=5) -> mm
    conv1x1_k<0><<<dim3(npix_blocks,2), 256, 0, stream>>>(x_mid, nullptr, w_pre_mid,
                                                  nullptr, nullptr, nullptr, hp);
    offmod_tile_k<5,2><<<BB*144*2, 256, 0, stream>>>(
        hp, w_off_mid, b_off_mid, w_mod_mid, b_mod_mid, om);
    make_wtb_k<5><<<25, 512, 0, stream>>>(w_reg_mid, wtb);
    deform_mfma_k<5><<<dfm_blocks, 512, 0, stream>>>(hp, om, wtb, mm);

    // ---- small branch (K=3) -> sm
    conv1x1_k<0><<<dim3(npix_blocks,2), 256, 0, stream>>>(x_small, nullptr, w_pre_small,
                                                  nullptr, nullptr, nullptr, hp);
    offmod_tile_k<3,1><<<BB*144*1, 256, 0, stream>>>(
        hp, w_off_small, b_off_small, w_mod_small, b_mod_small, om);
    make_wtb_k<3><<<9, 512, 0, stream>>>(w_reg_small, wtb);
    deform_mfma_k<3><<<dfm_blocks, 512, 0, stream>>>(hp, om, wtb, sm);

    // ---- combine
    conv1x1_k<1><<<dim3(npix_blocks,2), 256, 0, stream>>>(out, mm, w1,
                                                  nullptr, nullptr, nullptr, u);
    conv1x1_k<2><<<dim3(npix_blocks,2), 256, 0, stream>>>(u, sm, w2,
                                                  x_max, x_mid, x_small, out);
}

// Round 6
// 618.843 us; speedup vs baseline: 13.7974x; 1.6337x over previous
//
#include <hip/hip_runtime.h>
#include <math.h>

// Geometry (fixed by the reference)
#define BB   2
#define CC   64
#define HH   192
#define WW   192
#define HW   (HH*WW)          // 36864
#define HALO 3
#define HP   (HH + 2*HALO)    // 198
#define WP   (WW + 2*HALO)    // 198
#define PLANE (HP*WP)         // 39204

typedef __attribute__((ext_vector_type(8))) short bf16x8;
typedef __attribute__((ext_vector_type(8))) unsigned short u16x8;
typedef __attribute__((ext_vector_type(4))) float f32x4;

__device__ __forceinline__ unsigned short f2bf(float f) {
    union { float f; unsigned u; } x; x.f = f;
    unsigned r = (x.u + 0x7fffu + ((x.u >> 16) & 1u)) >> 16;   // RNE
    return (unsigned short)r;
}
__device__ __forceinline__ float b2f(unsigned short u) {
    union { unsigned u; float f; } x; x.u = ((unsigned)u) << 16;
    return x.f;
}
__device__ __forceinline__ float fast_tanh(float x) {
    float e = __expf(2.f * x);
    return 1.f - 2.f * __builtin_amdgcn_rcpf(e + 1.f);
}

// ---------------------------------------------------------------------------
// 1x1 conv (64->64) with fused epilogues, split 2-way over outputs.
// MODE 0: out = relu(W @ X) -> PADDED channel-interleaved bf16 hp8 layout
//         hp8[b][g][y][x][8ch], g = c>>3  (16B per (x,g))
// MODE 1: out = relu(W @ (X * tanh(M)))  -> flat f32 layout
// MODE 2: out = relu(W @ (X * tanh(M))) + Y0+Y1+Y2 -> flat f32 layout
// ---------------------------------------------------------------------------
template<int MODE>
__global__ __launch_bounds__(256) void conv1x1_k(
    const float* __restrict__ X, const float* __restrict__ M2,
    const float* __restrict__ W,
    const float* __restrict__ Y0, const float* __restrict__ Y1,
    const float* __restrict__ Y2,
    float* __restrict__ out)
{
    __shared__ float wl[64*32];   // [c][o_half]
    int tid = threadIdx.x;
    int oh  = blockIdx.y;         // output half
    #pragma unroll
    for (int n = 0; n < 8; n++) {
        int idx = tid + n*256;            // [0,2048)
        int op  = idx >> 6, c = idx & 63;
        wl[c*32 + op] = W[(size_t)(oh*32 + op)*64 + c];
    }
    __syncthreads();

    int p  = blockIdx.x*256 + tid;   // [0, BB*HW)
    int b  = p / HW;
    int pp = p - b*HW;

    const float* xb = X + (size_t)b*CC*HW + pp;
    const float* mb = (MODE >= 1) ? (M2 + (size_t)b*CC*HW + pp) : nullptr;

    float acc[32];
    #pragma unroll
    for (int o = 0; o < 32; o++) acc[o] = 0.f;

    for (int c = 0; c < 64; c++) {
        float xv = xb[(size_t)c*HW];
        if (MODE >= 1) xv *= fast_tanh(mb[(size_t)c*HW]);
        const float4* w4 = (const float4*)(wl + c*32);
        #pragma unroll
        for (int q = 0; q < 8; q++) {
            float4 w = w4[q];
            acc[4*q+0] = fmaf(w.x, xv, acc[4*q+0]);
            acc[4*q+1] = fmaf(w.y, xv, acc[4*q+1]);
            acc[4*q+2] = fmaf(w.z, xv, acc[4*q+2]);
            acc[4*q+3] = fmaf(w.w, xv, acc[4*q+3]);
        }
    }

    if (MODE == 0) {
        int y = pp / WW, x = pp - y*WW;
        u16x8* hp8 = (u16x8*)out;
        #pragma unroll
        for (int gq = 0; gq < 4; gq++) {
            u16x8 v;
            #pragma unroll
            for (int c = 0; c < 8; c++) v[c] = f2bf(fmaxf(acc[gq*8+c], 0.f));
            hp8[(size_t)(b*8 + oh*4 + gq)*PLANE + (size_t)(y+HALO)*WP + (x+HALO)] = v;
        }
    } else if (MODE == 1) {
        float* op = out + (size_t)b*CC*HW + (size_t)(oh*32)*HW + pp;
        #pragma unroll
        for (int o = 0; o < 32; o++) op[(size_t)o*HW] = fmaxf(acc[o], 0.f);
    } else {
        float* op = out + (size_t)b*CC*HW + (size_t)(oh*32)*HW + pp;
        size_t gi = (size_t)b*CC*HW + (size_t)(oh*32)*HW + pp;
        #pragma unroll
        for (int o = 0; o < 32; o++) {
            float yv = Y0[gi + (size_t)o*HW] + Y1[gi + (size_t)o*HW] + Y2[gi + (size_t)o*HW];
            op[(size_t)o*HW] = fmaxf(acc[o], 0.f) + yv;
        }
    }
}

// ---------------------------------------------------------------------------
// Offset + mask KxK conv, LDS-tiled, XCD-swizzled 1D grid. Stages from hp8
// (bf16 interleaved) converting to f32 in LDS.
// ---------------------------------------------------------------------------
template<int K, int TB>
__global__ __launch_bounds__(256) void offmod_tile_k(
    const u16x8* __restrict__ hp8,
    const float* __restrict__ Woff, const float* __restrict__ Boff,
    const float* __restrict__ Wmod, const float* __restrict__ Bmod,
    float* __restrict__ om)
{
    constexpr int PAD   = K/2;
    constexpr int KK    = K*K;
    constexpr int TD    = 16 + 2*PAD;
    constexpr int CCH   = 8;
    constexpr int NTAPS = (KK + TB - 1)/TB;
    constexpr int NT    = HW/256;   // 144 tiles

    __shared__ float tile[CCH][TD][TD];
    __shared__ float wb[NTAPS][CC][4];

    int raw = blockIdx.x;
    int N   = BB*NT*TB;
    int swz = (raw & 7)*(N >> 3) + (raw >> 3);
    int g   = swz % TB;
    int rem = swz / TB;
    int bt  = rem % NT;
    int b   = rem / NT;

    int tx = bt % (WW/16), ty = bt / (WW/16);
    int x0 = tx*16, y0 = ty*16;
    int tid = threadIdx.x;
    int lx = tid & 15, ly = tid >> 4;
    int t0 = g*NTAPS;

    for (int idx = tid; idx < NTAPS*CC; idx += 256) {
        int t = idx / CC, c = idx - (idx/CC)*CC;
        int tap = min(t0 + t, KK-1);
        wb[t][c][0] = Woff[(size_t)(2*tap  )*CC*KK + c*KK + tap];
        wb[t][c][1] = Woff[(size_t)(2*tap+1)*CC*KK + c*KK + tap];
        wb[t][c][2] = Wmod[(size_t)tap*CC*KK + c*KK + tap];
        wb[t][c][3] = 0.f;
    }

    float accy[NTAPS], accx[NTAPS], accm[NTAPS];
    #pragma unroll
    for (int t = 0; t < NTAPS; t++) {
        int tap = min(t0 + t, KK-1);
        accy[t] = Boff[2*tap];
        accx[t] = Boff[2*tap+1];
        accm[t] = Bmod[tap];
    }

    for (int cc = 0; cc < CC; cc += CCH) {
        __syncthreads();
        for (int idx = tid; idx < TD*TD; idx += 256) {
            int r   = idx / TD;
            int col = idx - r*TD;
            u16x8 v = hp8[(size_t)(b*8 + (cc>>3))*PLANE
                          + (size_t)(y0 + HALO - PAD + r)*WP
                          + (x0 + HALO - PAD + col)];
            #pragma unroll
            for (int c = 0; c < 8; c++) tile[c][r][col] = b2f(v[c]);
        }
        __syncthreads();

        #pragma unroll
        for (int c = 0; c < CCH; c++) {
            #pragma unroll
            for (int t = 0; t < NTAPS; t++) {
                int tap = min(t0 + t, KK-1);
                int i = tap / K, j = tap - (tap/K)*K;
                float v = tile[c][ly + i][lx + j];
                float4 w = *(const float4*)&wb[t][cc + c][0];
                accy[t] = fmaf(w.x, v, accy[t]);
                accx[t] = fmaf(w.y, v, accx[t]);
                accm[t] = fmaf(w.z, v, accm[t]);
            }
        }
    }

    int px = (y0 + ly)*WW + x0 + lx;
    float* ob = om + (size_t)b*3*KK*HW + px;
    #pragma unroll
    for (int t = 0; t < NTAPS; t++) {
        int tap = t0 + t;
        if (tap < KK) {
            ob[(size_t)(2*tap  )*HW] = accy[t];
            ob[(size_t)(2*tap+1)*HW] = accx[t];
            ob[(size_t)(2*KK+tap)*HW] = 2.f * __builtin_amdgcn_rcpf(1.f + __expf(-accm[t]));
        }
    }
}

// ---------------------------------------------------------------------------
// Pre-bake w_reg [o][c][K][K] into MFMA B-fragment order, bf16.
// ---------------------------------------------------------------------------
template<int K>
__global__ __launch_bounds__(512) void make_wtb_k(
    const float* __restrict__ Wreg, bf16x8* __restrict__ wtb)
{
    constexpr int KK = K*K;
    int t   = blockIdx.x;
    int tid = threadIdx.x;
    int kk  = tid >> 8;
    int rem = tid & 255;
    int ot  = rem >> 6;
    int l   = rem & 63;
    int lr  = l & 15, lg = l >> 4;
    int o   = ot*16 + lr;
    bf16x8 v;
    #pragma unroll
    for (int j = 0; j < 8; j++) {
        int c = kk*32 + lg*8 + j;
        v[j] = (short)f2bf(Wreg[((size_t)o*CC + c)*KK + t]);
    }
    wtb[(size_t)t*8*64 + (size_t)(kk*4 + ot)*64 + l] = v;
}

// ---------------------------------------------------------------------------
// Deformable sampling + MFMA channel matmul, hp8 interleaved-bf16 input.
// 512 thr = 8 waves: pxg = wave&3 (16-px group), half = wave>>2 (tap half).
// Per tap per lane: 8 aligned dwordx4 gathers (2 ch-groups x 2 rows x 2 x),
// fp32 bilinear blend, f2bf, 8 MFMA. Halves reduced via LDS.
// ---------------------------------------------------------------------------
template<int K>
__global__ __launch_bounds__(512) void deform_mfma_k(
    const u16x8* __restrict__ hp8,
    const float* __restrict__ om,
    const bf16x8* __restrict__ wtb,
    float* __restrict__ out)
{
    constexpr int PAD = K/2;
    constexpr int KK  = K*K;
    constexpr int NB  = HW/64;      // 576 strips per batch
    __shared__ float red[4][64][16];   // [pxg][o][px]

    int raw = blockIdx.x;            // [0, 2*NB)
    int swz = (raw & 7)*((2*NB) >> 3) + (raw >> 3);
    int b = swz / NB, strip = swz - b*NB;

    int tid  = threadIdx.x;
    int wave = tid >> 6;
    int l    = tid & 63;
    int lg   = l >> 4;
    int lr   = l & 15;
    int pxg  = wave & 3;
    int half = wave >> 2;
    int pxbase = strip*64 + pxg*16;
    int px   = pxbase + lr;
    int y    = px / WW, x = px - y*WW;

    int t0 = half ? (KK/2) : 0;
    int t1 = half ? KK : (KK/2);

    f32x4 acc[4];
    #pragma unroll
    for (int ot = 0; ot < 4; ot++) acc[ot] = (f32x4)0.f;

    const float* omb = om + (size_t)b*3*KK*HW + px;
    const u16x8* hb  = hp8 + (size_t)(b*8)*PLANE;

    #pragma unroll 1
    for (int t = t0; t < t1; t++) {
        int i = t / K, j = t - (t/K)*K;
        float offy = omb[(size_t)(2*t  )*HW];
        float offx = omb[(size_t)(2*t+1)*HW];
        float mk   = omb[(size_t)(2*KK+t)*HW];

        float py = (float)(y - PAD + i) + offy;
        float pxf= (float)(x - PAD + j) + offx;
        float fy = floorf(py), fx = floorf(pxf);
        float wy1 = py - fy, wx1 = pxf - fx;
        float wy0 = 1.f - wy1, wx0 = 1.f - wx1;
        int iy0 = (int)fy, ix0 = (int)fx;

        // clamp to [-1,192]: clamped loads land in the zero halo.
        int Y0 = min(max(iy0, -1), HH) + HALO;   // [2,195]
        int X0 = min(max(ix0, -1), WW) + HALO;   // [2,195]
        int r0 = Y0*WP + X0;

        float w00 = wy0*wx0*mk;
        float w01 = wy0*wx1*mk;
        float w10 = wy1*wx0*mk;
        float w11 = wy1*wx1*mk;

        // 8 aligned 16B gathers: group g = kk*4+lg (channels kk*32+lg*8..+7)
        u16x8 r[2][4];
        #pragma unroll
        for (int kk = 0; kk < 2; kk++) {
            const u16x8* G = hb + (size_t)(kk*4 + lg)*PLANE + r0;
            r[kk][0] = G[0];
            r[kk][1] = G[1];
            r[kk][2] = G[WP];
            r[kk][3] = G[WP+1];
        }

        bf16x8 afrag[2];
        #pragma unroll
        for (int kk = 0; kk < 2; kk++) {
            #pragma unroll
            for (int c = 0; c < 8; c++) {
                float s = b2f(r[kk][0][c]) * w00;
                s = fmaf(b2f(r[kk][1][c]), w01, s);
                s = fmaf(b2f(r[kk][2][c]), w10, s);
                s = fmaf(b2f(r[kk][3][c]), w11, s);
                afrag[kk][c] = (short)f2bf(s);
            }
        }

        const bf16x8* bp = wtb + (size_t)t*8*64 + l;
        #pragma unroll
        for (int kk = 0; kk < 2; kk++) {
            #pragma unroll
            for (int ot = 0; ot < 4; ot++) {
                acc[ot] = __builtin_amdgcn_mfma_f32_16x16x32_bf16(
                    afrag[kk], bp[(size_t)(kk*4 + ot)*64], acc[ot], 0, 0, 0);
            }
        }
    }

    // reduce tap halves through LDS, then store.
    // C/D layout: o = ot*16 + lr, px = pxbase + lg*4 + reg
    if (half == 1) {
        #pragma unroll
        for (int ot = 0; ot < 4; ot++)
            *reinterpret_cast<f32x4*>(&red[pxg][ot*16 + lr][lg*4]) = acc[ot];
    }
    __syncthreads();
    if (half == 0) {
        float* ob = out + (size_t)b*CC*HW + pxbase + lg*4;
        #pragma unroll
        for (int ot = 0; ot < 4; ot++) {
            f32x4 rr = *reinterpret_cast<const f32x4*>(&red[pxg][ot*16 + lr][lg*4]);
            rr += acc[ot];
            float4 v;
            v.x = rr[0]; v.y = rr[1]; v.z = rr[2]; v.w = rr[3];
            *reinterpret_cast<float4*>(ob + (size_t)(ot*16 + lr)*HW) = v;
        }
    }
}

// ---------------------------------------------------------------------------
// Launch. Workspace:
//   hp8: 2*8*PLANE u16x8 (16B)   = ~10.0 MB   (bf16 interleaved padded h)
//   om : 2*3*49*HW  f32          = ~43.4 MB   (reused as u after last deform)
//   mm : 2*64*HW    f32          = ~18.9 MB
//   sm : 2*64*HW    f32          = ~18.9 MB
//   wtb: 49*512 bf16x8           = ~0.4 MB
// ---------------------------------------------------------------------------
extern "C" void kernel_launch(void* const* d_in, const int* in_sizes, int n_in,
                              void* d_out, int out_size, void* d_ws, size_t ws_size,
                              hipStream_t stream)
{
    const float* x_max      = (const float*)d_in[0];
    const float* x_mid      = (const float*)d_in[1];
    const float* x_small    = (const float*)d_in[2];
    const float* w_pre_max  = (const float*)d_in[3];
    const float* w_off_max  = (const float*)d_in[4];
    const float* b_off_max  = (const float*)d_in[5];
    const float* w_mod_max  = (const float*)d_in[6];
    const float* b_mod_max  = (const float*)d_in[7];
    const float* w_reg_max  = (const float*)d_in[8];
    const float* w_pre_mid  = (const float*)d_in[9];
    const float* w_off_mid  = (const float*)d_in[10];
    const float* b_off_mid  = (const float*)d_in[11];
    const float* w_mod_mid  = (const float*)d_in[12];
    const float* b_mod_mid  = (const float*)d_in[13];
    const float* w_reg_mid  = (const float*)d_in[14];
    const float* w_pre_small= (const float*)d_in[15];
    const float* w_off_small= (const float*)d_in[16];
    const float* b_off_small= (const float*)d_in[17];
    const float* w_mod_small= (const float*)d_in[18];
    const float* b_mod_small= (const float*)d_in[19];
    const float* w_reg_small= (const float*)d_in[20];
    const float* w1         = (const float*)d_in[21];
    const float* w2         = (const float*)d_in[22];

    float* out = (float*)d_out;
    float* ws  = (float*)d_ws;
    u16x8* hp8 = (u16x8*)ws;
    float* om  = ws + (size_t)BB*8*PLANE*4;   // hp8 = BB*8*PLANE*16B
    float* mm  = om + (size_t)BB*3*49*HW;
    float* sm  = mm + (size_t)BB*CC*HW;
    bf16x8* wtb= (bf16x8*)(sm + (size_t)BB*CC*HW);
    float* u   = om;   // om dead after last deform

    hipMemsetAsync(hp8, 0, (size_t)BB*8*PLANE*sizeof(u16x8), stream);

    const int npix_blocks = (BB*HW)/256;   // 288
    const int dfm_blocks  = BB*(HW/64);    // 1152

    // ---- max branch (K=7) -> a in d_out
    conv1x1_k<0><<<dim3(npix_blocks,2), 256, 0, stream>>>(x_max, nullptr, w_pre_max,
                                                  nullptr, nullptr, nullptr, (float*)hp8);
    offmod_tile_k<7,4><<<BB*144*4, 256, 0, stream>>>(
        hp8, w_off_max, b_off_max, w_mod_max, b_mod_max, om);
    make_wtb_k<7><<<49, 512, 0, stream>>>(w_reg_max, wtb);
    deform_mfma_k<7><<<dfm_blocks, 512, 0, stream>>>(hp8, om, wtb, out);

    // ---- mid branch (K=5) -> mm
    conv1x1_k<0><<<dim3(npix_blocks,2), 256, 0, stream>>>(x_mid, nullptr, w_pre_mid,
                                                  nullptr, nullptr, nullptr, (float*)hp8);
    offmod_tile_k<5,2><<<BB*144*2, 256, 0, stream>>>(
        hp8, w_off_mid, b_off_mid, w_mod_mid, b_mod_mid, om);
    make_wtb_k<5><<<25, 512, 0, stream>>>(w_reg_mid, wtb);
    deform_mfma_k<5><<<dfm_blocks, 512, 0, stream>>>(hp8, om, wtb, mm);

    // ---- small branch (K=3) -> sm
    conv1x1_k<0><<<dim3(npix_blocks,2), 256, 0, stream>>>(x_small, nullptr, w_pre_small,
                                                  nullptr, nullptr, nullptr, (float*)hp8);
    offmod_tile_k<3,1><<<BB*144*1, 256, 0, stream>>>(
        hp8, w_off_small, b_off_small, w_mod_small, b_mod_small, om);
    make_wtb_k<3><<<9, 512, 0, stream>>>(w_reg_small, wtb);
    deform_mfma_k<3><<<dfm_blocks, 512, 0, stream>>>(hp8, om, wtb, sm);

    // ---- combine
    conv1x1_k<1><<<dim3(npix_blocks,2), 256, 0, stream>>>(out, mm, w1,
                                                  nullptr, nullptr, nullptr, u);
    conv1x1_k<2><<<dim3(npix_blocks,2), 256, 0, stream>>>(u, sm, w2,
                                                  x_max, x_mid, x_small, out);
}